// Round 3
// baseline (1059.519 us; speedup 1.0000x reference)
//
#include <hip/hip_runtime.h>
#include <cmath>

// ---------------------------------------------------------------------------
// RPN head post-processing (mmdet GetBboxes-style), exact-semantics HIP port.
//
// Correctness strategy: all ordering-critical math is fp64-exact (sigmoid,
// delta2bbox) or fp64-equivalent (IoU predicate: fp32 filter + fp64 fallback
// inside a conservative error band); within-level top-k ordering uses raw
// fp32 logit bits (monotone-equivalent to fp64 sigmoid ordering, ties ->
// lower index, matching lax.top_k / stable argsort).
//
// R1: register-resident greedy -> SPILLED (VGPR cap 128, M[64]=128 VGPRs);
//     2048-step dependent scratch-load chain = 248us.
// R2: greedy = distributed-bitmask serial scan: lane j<32 holds supp word j;
//     per row one ballot broadcast (~20cy chain), mask rows arrive via
//     triple-buffered 16-row prefetch (96 VGPRs total). k_iou: fp32
//     predicate + fp64 fallback band, strided row balance, upper-tri only.
// ---------------------------------------------------------------------------

#define NPRE 2000
#define NPOST 1000

static __device__ __forceinline__ unsigned int flipf_dev(float f) {
  unsigned int u = __float_as_uint(f);
  return (u & 0x80000000u) ? ~u : (u | 0x80000000u);
}
static __device__ __forceinline__ float unflipf_dev(unsigned int k) {
  unsigned int u = (k & 0x80000000u) ? (k ^ 0x80000000u) : ~k;
  return __uint_as_float(u);
}
static __device__ __forceinline__ unsigned long long flip64_dev(double d) {
  unsigned long long u = (unsigned long long)__double_as_longlong(d);
  return (u & 0x8000000000000000ull) ? ~u : (u | 0x8000000000000000ull);
}

struct RPNParams {
  const float* cls[5];
  const float* bbox[5];
  const float* anc[5];
  unsigned int* hist;          // [10][65536]
  unsigned int* mainCount;     // [10]
  unsigned int* candCount;     // [10]
  unsigned int* Bstar;         // [10]
  unsigned long long* mainEK;  // [10][2048]  packed (key<<32)|~idx
  unsigned long long* candEK;  // [10][8192]
  double* selBoxes;            // [10][2000][4]
  double* selScores;           // [10][2000]
  unsigned long long* mask;    // [10][2000][32]
  unsigned long long* keeps;   // [10][32]
  double* postScores;          // [10][1000]
  float* postBoxes;            // [10][1000][4]
  unsigned int* partial;       // [16][5000]
  float* out;                  // [2][1000][4]
};

__device__ __constant__ int c_NL[5]  = {201600, 50400, 12600, 3150, 819};
__device__ __constant__ int c_HW[5]  = {67200, 16800, 4200, 1050, 273};
// blocks-per-task for the 8 tasks with N>=2000 (levels 0..3 x 2 images)
__device__ __constant__ int c_BPT[8] = {50, 50, 13, 13, 4, 4, 1, 1};

static __device__ __forceinline__ void map_block(int bx, int& t, int& chunk) {
  int start = 0;
  t = 0;
  for (int k = 0; k < 8; k++) {
    if (bx < start + c_BPT[k]) { t = k; break; }
    start += c_BPT[k];
  }
  chunk = bx - start;
}

// --- 1. per-task 16-bit-bucket histogram of flipped logit keys --------------
__global__ void k_hist(RPNParams p) {
  int t, chunk;
  map_block(blockIdx.x, t, chunk);
  int l = t >> 1, b = t & 1;
  int N = c_NL[l], HW = c_HW[l];
  const float* cls = p.cls[l] + (size_t)b * 3 * HW;
  unsigned int* hist = p.hist + (size_t)t * 65536;
  int base = chunk * 4096 + threadIdx.x;
  for (int k = 0; k < 4; k++) {
    int n = base + k * 1024;
    if (n < N) {
      int a = n % 3, hw = n / 3;
      unsigned int key = flipf_dev(cls[a * HW + hw]);
      atomicAdd(&hist[key >> 16], 1u);
    }
  }
}

// --- 2. find threshold bucket B* per task (suffix-sum over 65536 buckets) ---
__global__ void k_find(RPNParams p) {
  int t = blockIdx.x;  // 0..7
  unsigned int* hist = p.hist + (size_t)t * 65536;
  __shared__ unsigned int S[1024];
  __shared__ int gsel;
  __shared__ unsigned int baseAbove;
  int g = threadIdx.x;
  unsigned int s = 0;
  for (int j = 0; j < 64; j++) s += hist[g * 64 + j];
  S[g] = s;
  __syncthreads();
  for (int off = 1; off < 1024; off <<= 1) {
    unsigned int add = (g + off < 1024) ? S[g + off] : 0u;
    __syncthreads();
    S[g] += add;
    __syncthreads();
  }
  const unsigned int need = NPRE;
  if (S[g] >= need && (g == 1023 || S[g + 1] < need)) {
    gsel = g;
    baseAbove = (g == 1023) ? 0u : S[g + 1];
  }
  __syncthreads();
  if (threadIdx.x == 0) {
    int gg = gsel;
    unsigned int c = baseAbove;
    int bstar = gg * 64;
    for (int bb = gg * 64 + 63; bb >= gg * 64; bb--) {
      c += hist[bb];
      if (c >= need) { bstar = bb; break; }
    }
    p.Bstar[t] = (unsigned int)bstar;
  }
}

// --- 3. compaction: strictly-above bucket -> main list, == bucket -> cand ---
__global__ void k_compact(RPNParams p) {
  int t, chunk;
  map_block(blockIdx.x, t, chunk);
  int l = t >> 1, b = t & 1;
  int N = c_NL[l], HW = c_HW[l];
  const float* cls = p.cls[l] + (size_t)b * 3 * HW;
  unsigned int Bs = p.Bstar[t];
  int base = chunk * 4096 + threadIdx.x;
  for (int k = 0; k < 4; k++) {
    int n = base + k * 1024;
    if (n < N) {
      int a = n % 3, hw = n / 3;
      unsigned int key = flipf_dev(cls[a * HW + hw]);
      unsigned int hi = key >> 16;
      unsigned long long ek =
          ((unsigned long long)key << 32) | (unsigned int)(~(unsigned int)n);
      if (hi > Bs) {
        unsigned int pos = atomicAdd(&p.mainCount[t], 1u);
        if (pos < 2048u) p.mainEK[(size_t)t * 2048 + pos] = ek;
      } else if (hi == Bs) {
        unsigned int pos = atomicAdd(&p.candCount[t], 1u);
        if (pos < 8192u) p.candEK[(size_t)t * 8192 + pos] = ek;
      }
    }
  }
}

// --- 4. assemble exact top-2000, counting-rank sort, fp64 decode ------------
__global__ void k_assemble(RPNParams p) {
  int t = blockIdx.x;  // 0..9
  int l = t >> 1, b = t & 1;
  int N = c_NL[l], HW = c_HW[l];
  __shared__ unsigned long long ekA[2048];
  __shared__ unsigned long long srt[2048];
  int tid = threadIdx.x;

  if (N >= NPRE) {
    unsigned int cGT = min(p.mainCount[t], 2000u);
    unsigned int nC = min(p.candCount[t], 8192u);
    unsigned int needIn = 2000u - cGT;
    for (unsigned int m = tid; m < cGT; m += 1024)
      ekA[m] = p.mainEK[(size_t)t * 2048 + m];
    const unsigned long long* cek = p.candEK + (size_t)t * 8192;
    for (unsigned int e = tid; e < nC; e += 1024) {
      unsigned long long ve = cek[e];
      unsigned int r = 0;
      for (unsigned int j = 0; j < nC; j++) r += (cek[j] > ve) ? 1u : 0u;
      if (r < needIn) ekA[cGT + r] = ve;
    }
    for (unsigned int r = 2000u + tid; r < 2048u; r += 1024)
      ekA[r] = (unsigned long long)(unsigned int)(~r);  // key=0 pads, idx=r
  } else {
    // level 4: reference pads to 2000 with score=-1, zero deltas/anchors,
    // top_i = arange. Equivalent to key sort with pad key = 0.
    const float* cls = p.cls[l] + (size_t)b * 3 * HW;
    for (int r = tid; r < 2048; r += 1024) {
      if (r < N) {
        int a = r % 3, hw = r / 3;
        unsigned int key = flipf_dev(cls[a * HW + hw]);
        ekA[r] = ((unsigned long long)key << 32) |
                 (unsigned int)(~(unsigned int)r);
      } else {
        ekA[r] = (unsigned long long)(unsigned int)(~(unsigned int)r);
      }
    }
  }
  __syncthreads();

  // counting-rank sort (desc by key, asc by idx; packed u64 compare).
  {
    unsigned long long v0 = ekA[tid], v1 = ekA[tid + 1024];
    int r0 = 0, r1 = 0;
    for (int j = 0; j < 2048; j++) {
      unsigned long long vj = ekA[j];
      r0 += (vj > v0) ? 1 : 0;
      r1 += (vj > v1) ? 1 : 0;
    }
    srt[r0] = v0;
    srt[r1] = v1;
  }
  __syncthreads();

  const double RCLIP = fabs(log(16.0 / 1000.0));  // mmdet wh_ratio_clip
  const float* bbx = p.bbox[l] + (size_t)b * 12 * HW;
  const float* anc = p.anc[l];
  for (int r = tid; r < NPRE; r += 1024) {
    unsigned long long v = srt[r];
    unsigned int key = (unsigned int)(v >> 32);
    double* SB = p.selBoxes + ((size_t)t * NPRE + r) * 4;
    if (key == 0u) {  // pad: zero anchors/deltas -> zero box, score -1
      SB[0] = 0.0; SB[1] = 0.0; SB[2] = 0.0; SB[3] = 0.0;
      p.selScores[(size_t)t * NPRE + r] = -1.0;
    } else {
      unsigned int idx = ~(unsigned int)(v & 0xFFFFFFFFull);
      int a = (int)(idx % 3u);
      int hw = (int)(idx / 3u);
      double d0 = (double)bbx[(a * 4 + 0) * HW + hw];
      double d1 = (double)bbx[(a * 4 + 1) * HW + hw];
      double d2 = (double)bbx[(a * 4 + 2) * HW + hw];
      double d3 = (double)bbx[(a * 4 + 3) * HW + hw];
      double a0 = (double)anc[(size_t)idx * 4 + 0];
      double a1 = (double)anc[(size_t)idx * 4 + 1];
      double a2 = (double)anc[(size_t)idx * 4 + 2];
      double a3 = (double)anc[(size_t)idx * 4 + 3];
      double dw = fmin(fmax(d2, -RCLIP), RCLIP);
      double dh = fmin(fmax(d3, -RCLIP), RCLIP);
      double pw = a2 - a0, ph = a3 - a1;
      double px = (a0 + a2) * 0.5, py = (a1 + a3) * 0.5;
      double gw = pw * exp(dw), gh = ph * exp(dh);
      double gx = px + pw * d0, gy = py + ph * d1;
      double x1 = fmin(fmax(gx - 0.5 * gw, 0.0), 1344.0);
      double y1 = fmin(fmax(gy - 0.5 * gh, 0.0), 800.0);
      double x2 = fmin(fmax(gx + 0.5 * gw, 0.0), 1344.0);
      double y2 = fmin(fmax(gy + 0.5 * gh, 0.0), 800.0);
      SB[0] = x1; SB[1] = y1; SB[2] = x2; SB[3] = y2;
      float f = unflipf_dev(key);
      p.selScores[(size_t)t * NPRE + r] = 1.0 / (1.0 + exp(-(double)f));
    }
  }
}

// --- 5. IoU -> suppression bitmask. fp32 predicate + fp64 fallback band. ----
// Rows strided across blocks for balance; only upper-triangle words
// (k >= i>>6) are written -- k_greedy masks lower words to zero.
__global__ void k_iou(RPNParams p) {
  int bx = blockIdx.x;  // 200 blocks = 20 per task
  int t = bx / 20;
  int q = bx % 20;
  __shared__ float X1[2000], Y1[2000], X2[2000], Y2[2000], AR[2000];
  const double* SB = p.selBoxes + (size_t)t * NPRE * 4;
  for (int i = threadIdx.x; i < NPRE; i += 256) {
    float x1 = (float)SB[i * 4 + 0], y1 = (float)SB[i * 4 + 1];
    float x2 = (float)SB[i * 4 + 2], y2 = (float)SB[i * 4 + 3];
    X1[i] = x1; Y1[i] = y1; X2[i] = x2; Y2[i] = y2;
    AR[i] = (x2 - x1) * (y2 - y1);
  }
  __syncthreads();
  int wave = threadIdx.x >> 6, lane = threadIdx.x & 63;
  for (int s = 0; s < 25; s++) {
    int i = q + 20 * (wave + 4 * s);  // strided: balances (2000-i) work
    float x1i = X1[i], y1i = Y1[i], x2i = X2[i], y2i = Y2[i], ai = AR[i];
    int c0 = i >> 6;
    for (int k = c0; k < 32; k++) {
      int j = k * 64 + lane;
      bool pred = false;
      if (j > i && j < NPRE) {
        float lx = fmaxf(x1i, X1[j]), ly = fmaxf(y1i, Y1[j]);
        float rx = fminf(x2i, X2[j]), ry = fminf(y2i, Y2[j]);
        float w = fmaxf(rx - lx, 0.0f), h = fmaxf(ry - ly, 0.0f);
        float inter = w * h;
        float uni = fmaxf(ai + AR[j] - inter, 1e-6f);
        float diff = inter - 0.7f * uni;
        if (fabsf(diff) > 4.0f + 1e-5f * uni) {
          pred = diff > 0.0f;  // fp32 decision provably == fp64 decision
        } else {
          // exact fp64 fallback (rare: only near the 0.7 boundary)
          double a0 = SB[i * 4 + 0], b0 = SB[i * 4 + 1];
          double a2 = SB[i * 4 + 2], b2 = SB[i * 4 + 3];
          double c0d = SB[j * 4 + 0], d0 = SB[j * 4 + 1];
          double c2 = SB[j * 4 + 2], d2 = SB[j * 4 + 3];
          double dai = (a2 - a0) * (b2 - b0);
          double daj = (c2 - c0d) * (d2 - d0);
          double lxd = fmax(a0, c0d), lyd = fmax(b0, d0);
          double rxd = fmin(a2, c2), ryd = fmin(b2, d2);
          double wd = fmax(rxd - lxd, 0.0), hd = fmax(ryd - lyd, 0.0);
          double interd = wd * hd;
          double unid = fmax(dai + daj - interd, 1e-6);
          pred = (interd / unid) > 0.7;
        }
      }
      unsigned long long word = __ballot(pred);
      if (lane == 0) p.mask[((size_t)t * NPRE + i) * 32 + k] = word;
    }
  }
}

// --- 6. greedy NMS: distributed-bitmask serial scan, 1 wave per task --------
// Lane j<32 holds suppression word j (elements j*64..j*64+63) and keep word.
// Serial over i: owner lane (i>>6) tests its local bit; one ballot broadcasts
// the keep decision; all lanes OR their (prefetched) column word of row i.
// Triple-buffered 16-row groups keep ~32 rows of loads in flight (96 VGPRs).
__global__ __launch_bounds__(64) void k_greedy(RPNParams p) {
  int t = blockIdx.x;
  int lane = threadIdx.x;  // 64 = 1 wave
  const unsigned long long* MK = p.mask + (size_t)t * NPRE * 32;
  unsigned long long supp = 0ull, keep = 0ull;
  unsigned long long A[16], B[16], C[16];

  auto loadg = [&](unsigned long long* buf, int g) {
#pragma unroll
    for (int r = 0; r < 16; r++) {
      int row = g * 16 + r;
      buf[r] = (lane < 32) ? MK[(size_t)row * 32 + lane] : 0ull;
    }
  };
  auto procg = [&](unsigned long long* buf, int g) {
#pragma unroll
    for (int r = 0; r < 16; r++) {
      int i = g * 16 + r;
      int c = i >> 6;
      int b = i & 63;
      // lower-triangle words were never written by k_iou: mask them off-chain
      unsigned long long vv = (lane >= c) ? buf[r] : 0ull;
      bool pred = (lane == c) && (((supp >> b) & 1ull) == 0ull);
      unsigned long long kb = __ballot(pred);
      if (pred) keep |= 1ull << b;
      supp |= (kb != 0ull) ? vv : 0ull;
    }
  };

  loadg(A, 0);
  loadg(B, 1);
  for (int g = 0; g < 125; g += 3) {  // 125 groups of 16 rows = 2000
    if (g + 2 < 125) loadg(C, g + 2);
    procg(A, g);
    if (g + 3 < 125) loadg(A, g + 3);
    if (g + 1 < 125) procg(B, g + 1);
    if (g + 4 < 125) loadg(B, g + 4);
    if (g + 2 < 125) procg(C, g + 2);
  }
  if (lane < 32) p.keeps[(size_t)t * 32 + lane] = keep;
}

// --- 7. per-task re-rank: kept(+score) first (idx order), then -1 group -----
__global__ void k_post(RPNParams p) {
  int t = blockIdx.x;
  __shared__ unsigned long long kw[32], aw[32], bw[32];
  __shared__ unsigned int prefA[33], prefB[33];
  int tid = threadIdx.x;  // 256
  if (tid < 32) kw[tid] = p.keeps[(size_t)t * 32 + tid];
  __syncthreads();
  int wave = tid >> 6, lane = tid & 63;
  for (int ch = wave; ch < 32; ch += 4) {
    int i = ch * 64 + lane;
    bool inr = i < NPRE;
    bool kb = inr && ((kw[ch] >> lane) & 1ull);
    bool A = kb && (inr ? (p.selScores[(size_t)t * NPRE + i] > -0.5) : false);
    bool B = inr && !A;
    unsigned long long wa = __ballot(A);
    unsigned long long wb = __ballot(B);
    if (lane == 0) { aw[ch] = wa; bw[ch] = wb; }
  }
  __syncthreads();
  if (tid == 0) {
    unsigned int ca = 0, cb = 0;
    for (int w = 0; w < 32; w++) {
      prefA[w] = ca; ca += __popcll(aw[w]);
      prefB[w] = cb; cb += __popcll(bw[w]);
    }
    prefA[32] = ca; prefB[32] = cb;
  }
  __syncthreads();
  unsigned int KA = prefA[32];
  for (int i = tid; i < NPRE; i += 256) {
    int w = i >> 6, bpos = i & 63;
    unsigned long long below = (bpos == 0) ? 0ull : (~0ull >> (64 - bpos));
    bool kb = (kw[w] >> bpos) & 1ull;
    double s = p.selScores[(size_t)t * NPRE + i];
    bool A = kb && (s > -0.5);
    unsigned int slot;
    double outs;
    if (A) {
      slot = prefA[w] + (unsigned int)__popcll(aw[w] & below);
      outs = s;
    } else {
      slot = KA + prefB[w] + (unsigned int)__popcll(bw[w] & below);
      outs = -1.0;
    }
    if (slot < NPOST) {
      p.postScores[(size_t)t * NPOST + slot] = outs;
      const double* SB = p.selBoxes + ((size_t)t * NPRE + i) * 4;
      float* PB = p.postBoxes + ((size_t)t * NPOST + slot) * 4;
      PB[0] = (float)SB[0]; PB[1] = (float)SB[1];
      PB[2] = (float)SB[2]; PB[3] = (float)SB[3];
    }
  }
}

// --- 8a. final cross-level top-1000: sliced counting-rank -------------------
__global__ void k_finalA(RPNParams p) {
  int b = blockIdx.x >> 3;
  int s = blockIdx.x & 7;
  int j0 = s * 625;
  __shared__ unsigned long long kj[625];
  int tid = threadIdx.x;  // 1024
  for (int j = tid; j < 625; j += 1024) {
    int e = j0 + j;
    int l = e / 1000, slot = e % 1000;
    int t = l * 2 + b;
    kj[j] = flip64_dev(p.postScores[(size_t)t * NPOST + slot]);
  }
  __syncthreads();
  for (int e = tid; e < 5000; e += 1024) {
    int l = e / 1000, slot = e % 1000;
    int t = l * 2 + b;
    unsigned long long ke = flip64_dev(p.postScores[(size_t)t * NPOST + slot]);
    unsigned int r = 0;
    for (int j = 0; j < 625; j++) {
      unsigned long long v = kj[j];
      int jg = j0 + j;
      r += (v > ke || (v == ke && jg < e)) ? 1u : 0u;
    }
    p.partial[((size_t)b * 8 + s) * 5000 + e] = r;
  }
}

// --- 8b. reduce ranks, gather output boxes ----------------------------------
__global__ void k_finalB(RPNParams p) {
  int b = blockIdx.x;
  int tid = threadIdx.x;
  for (int e = tid; e < 5000; e += 1024) {
    unsigned int r = 0;
    for (int s = 0; s < 8; s++) r += p.partial[((size_t)b * 8 + s) * 5000 + e];
    if (r < NPOST) {
      int l = e / 1000, slot = e % 1000;
      int t = l * 2 + b;
      const float* PB = p.postBoxes + ((size_t)t * NPOST + slot) * 4;
      float* O = p.out + ((size_t)b * NPOST + r) * 4;
      O[0] = PB[0]; O[1] = PB[1]; O[2] = PB[2]; O[3] = PB[3];
    }
  }
}

extern "C" void kernel_launch(void* const* d_in, const int* in_sizes, int n_in,
                              void* d_out, int out_size, void* d_ws,
                              size_t ws_size, hipStream_t stream) {
  RPNParams p;
  bool interleaved = (n_in >= 2) && (in_sizes[1] == 4 * in_sizes[0]);
  for (int l = 0; l < 5; l++) {
    if (interleaved) {
      p.cls[l]  = (const float*)d_in[3 * l + 0];
      p.bbox[l] = (const float*)d_in[3 * l + 1];
      p.anc[l]  = (const float*)d_in[3 * l + 2];
    } else {
      p.cls[l]  = (const float*)d_in[l];
      p.bbox[l] = (const float*)d_in[5 + l];
      p.anc[l]  = (const float*)d_in[10 + l];
    }
  }
  char* w = (char*)d_ws;
  size_t off = 0;
  auto alloc = [&](size_t bytes) {
    off = (off + 255) & ~(size_t)255;
    void* r = w + off;
    off += bytes;
    return r;
  };
  p.hist      = (unsigned int*)alloc((size_t)10 * 65536 * 4);
  p.mainCount = (unsigned int*)alloc(10 * 4);
  p.candCount = (unsigned int*)alloc(10 * 4);
  size_t zbytes = off;  // zeroed region: hist + atomic counters
  p.Bstar      = (unsigned int*)alloc(10 * 4);
  p.mainEK     = (unsigned long long*)alloc((size_t)10 * 2048 * 8);
  p.candEK     = (unsigned long long*)alloc((size_t)10 * 8192 * 8);
  p.selBoxes   = (double*)alloc((size_t)10 * NPRE * 4 * 8);
  p.selScores  = (double*)alloc((size_t)10 * NPRE * 8);
  p.mask       = (unsigned long long*)alloc((size_t)10 * NPRE * 32 * 8);
  p.keeps      = (unsigned long long*)alloc((size_t)10 * 32 * 8);
  p.postScores = (double*)alloc((size_t)10 * NPOST * 8);
  p.postBoxes  = (float*)alloc((size_t)10 * NPOST * 4 * 4);
  p.partial    = (unsigned int*)alloc((size_t)16 * 5000 * 4);
  p.out = (float*)d_out;
  (void)ws_size; (void)out_size;

  hipMemsetAsync(d_ws, 0, zbytes, stream);
  k_hist<<<dim3(136), dim3(1024), 0, stream>>>(p);
  k_find<<<dim3(8), dim3(1024), 0, stream>>>(p);
  k_compact<<<dim3(136), dim3(1024), 0, stream>>>(p);
  k_assemble<<<dim3(10), dim3(1024), 0, stream>>>(p);
  k_iou<<<dim3(200), dim3(256), 0, stream>>>(p);
  k_greedy<<<dim3(10), dim3(64), 0, stream>>>(p);
  k_post<<<dim3(10), dim3(256), 0, stream>>>(p);
  k_finalA<<<dim3(16), dim3(1024), 0, stream>>>(p);
  k_finalB<<<dim3(2), dim3(1024), 0, stream>>>(p);
}

// Round 4
// 655.354 us; speedup vs baseline: 1.6167x; 1.6167x over previous
//
#include <hip/hip_runtime.h>
#include <cmath>

// ---------------------------------------------------------------------------
// RPN head post-processing (mmdet GetBboxes-style), exact-semantics HIP port.
//
// Correctness: ordering-critical math fp64-exact (sigmoid, delta2bbox) or
// fp64-equivalent (IoU: fp32 filter + fp64 fallback band); top-k ordering on
// raw fp32 logit bits (monotone == fp64 sigmoid order; ties -> lower index).
//
// R1/R2/R3 lesson: the serial greedy scan CANNOT hold a register prefetch
// pipeline (96+ VGPRs of buffers -> spill to scratch -> ~565cy/row; FETCH
// counter showed the scratch traffic). R4: producer/consumer wave
// specialization -- producer wave streams mask into an LDS ring (absorbs all
// global latency), consumer wave runs the closure from LDS with an
// owner-lane serial step + one shfl per 16-row group.
// R4 also splits the 2048^2 counting-rank (was 10 blocks, VALU-bound) into
// fill -> 80-block sliced rank -> scatter+decode.
// ---------------------------------------------------------------------------

#define NPRE 2000
#define NPOST 1000

static __device__ __forceinline__ unsigned int flipf_dev(float f) {
  unsigned int u = __float_as_uint(f);
  return (u & 0x80000000u) ? ~u : (u | 0x80000000u);
}
static __device__ __forceinline__ float unflipf_dev(unsigned int k) {
  unsigned int u = (k & 0x80000000u) ? (k ^ 0x80000000u) : ~k;
  return __uint_as_float(u);
}
static __device__ __forceinline__ unsigned long long flip64_dev(double d) {
  unsigned long long u = (unsigned long long)__double_as_longlong(d);
  return (u & 0x8000000000000000ull) ? ~u : (u | 0x8000000000000000ull);
}

struct RPNParams {
  const float* cls[5];
  const float* bbox[5];
  const float* anc[5];
  unsigned int* hist;          // [10][65536]
  unsigned int* mainCount;     // [10]
  unsigned int* candCount;     // [10]
  unsigned int* Bstar;         // [10]
  unsigned long long* mainEK;  // [10][2048]  packed (key<<32)|~idx
  unsigned long long* candEK;  // [10][8192]
  unsigned long long* ekG;     // [10][2048]  assembled top-2000 (+pads)
  unsigned int* partialR;      // [10][8][2048] sliced ranks
  double* selBoxes;            // [10][2000][4]
  double* selScores;           // [10][2000]
  unsigned long long* mask;    // [10][2000][32]
  unsigned long long* keeps;   // [10][32]
  double* postScores;          // [10][1000]
  float* postBoxes;            // [10][1000][4]
  unsigned int* partial;       // [16][5000]
  float* out;                  // [2][1000][4]
};

__device__ __constant__ int c_NL[5]  = {201600, 50400, 12600, 3150, 819};
__device__ __constant__ int c_HW[5]  = {67200, 16800, 4200, 1050, 273};
__device__ __constant__ int c_BPT[8] = {50, 50, 13, 13, 4, 4, 1, 1};

static __device__ __forceinline__ void map_block(int bx, int& t, int& chunk) {
  int start = 0;
  t = 0;
  for (int k = 0; k < 8; k++) {
    if (bx < start + c_BPT[k]) { t = k; break; }
    start += c_BPT[k];
  }
  chunk = bx - start;
}

// --- 1. per-task 16-bit-bucket histogram of flipped logit keys --------------
__global__ void k_hist(RPNParams p) {
  int t, chunk;
  map_block(blockIdx.x, t, chunk);
  int l = t >> 1, b = t & 1;
  int N = c_NL[l], HW = c_HW[l];
  const float* cls = p.cls[l] + (size_t)b * 3 * HW;
  unsigned int* hist = p.hist + (size_t)t * 65536;
  int base = chunk * 4096 + threadIdx.x;
  for (int k = 0; k < 4; k++) {
    int n = base + k * 1024;
    if (n < N) {
      int a = n % 3, hw = n / 3;
      unsigned int key = flipf_dev(cls[a * HW + hw]);
      atomicAdd(&hist[key >> 16], 1u);
    }
  }
}

// --- 2. find threshold bucket B* per task -----------------------------------
__global__ void k_find(RPNParams p) {
  int t = blockIdx.x;  // 0..7
  unsigned int* hist = p.hist + (size_t)t * 65536;
  __shared__ unsigned int S[1024];
  __shared__ int gsel;
  __shared__ unsigned int baseAbove;
  int g = threadIdx.x;
  unsigned int s = 0;
  for (int j = 0; j < 64; j++) s += hist[g * 64 + j];
  S[g] = s;
  __syncthreads();
  for (int off = 1; off < 1024; off <<= 1) {
    unsigned int add = (g + off < 1024) ? S[g + off] : 0u;
    __syncthreads();
    S[g] += add;
    __syncthreads();
  }
  const unsigned int need = NPRE;
  if (S[g] >= need && (g == 1023 || S[g + 1] < need)) {
    gsel = g;
    baseAbove = (g == 1023) ? 0u : S[g + 1];
  }
  __syncthreads();
  if (threadIdx.x == 0) {
    int gg = gsel;
    unsigned int c = baseAbove;
    int bstar = gg * 64;
    for (int bb = gg * 64 + 63; bb >= gg * 64; bb--) {
      c += hist[bb];
      if (c >= need) { bstar = bb; break; }
    }
    p.Bstar[t] = (unsigned int)bstar;
  }
}

// --- 3. compaction: above-bucket -> main, == bucket -> cand -----------------
__global__ void k_compact(RPNParams p) {
  int t, chunk;
  map_block(blockIdx.x, t, chunk);
  int l = t >> 1, b = t & 1;
  int N = c_NL[l], HW = c_HW[l];
  const float* cls = p.cls[l] + (size_t)b * 3 * HW;
  unsigned int Bs = p.Bstar[t];
  int base = chunk * 4096 + threadIdx.x;
  for (int k = 0; k < 4; k++) {
    int n = base + k * 1024;
    if (n < N) {
      int a = n % 3, hw = n / 3;
      unsigned int key = flipf_dev(cls[a * HW + hw]);
      unsigned int hi = key >> 16;
      unsigned long long ek =
          ((unsigned long long)key << 32) | (unsigned int)(~(unsigned int)n);
      if (hi > Bs) {
        unsigned int pos = atomicAdd(&p.mainCount[t], 1u);
        if (pos < 2048u) p.mainEK[(size_t)t * 2048 + pos] = ek;
      } else if (hi == Bs) {
        unsigned int pos = atomicAdd(&p.candCount[t], 1u);
        if (pos < 8192u) p.candEK[(size_t)t * 8192 + pos] = ek;
      }
    }
  }
}

// --- 4a. fill ekG[t][2048]: exact top-2000 keys + pads ----------------------
__global__ void k_fill(RPNParams p) {
  int t = blockIdx.x;  // 0..9
  int l = t >> 1, b = t & 1;
  int N = c_NL[l], HW = c_HW[l];
  int tid = threadIdx.x;  // 256
  unsigned long long* ekG = p.ekG + (size_t)t * 2048;
  if (N >= NPRE) {
    unsigned int cGT = min(p.mainCount[t], 2000u);
    unsigned int nC = min(p.candCount[t], 8192u);
    unsigned int needIn = 2000u - cGT;
    for (unsigned int m = tid; m < cGT; m += 256)
      ekG[m] = p.mainEK[(size_t)t * 2048 + m];
    const unsigned long long* cek = p.candEK + (size_t)t * 8192;
    for (unsigned int e = tid; e < nC; e += 256) {
      unsigned long long ve = cek[e];
      unsigned int r = 0;
      for (unsigned int j = 0; j < nC; j++) r += (cek[j] > ve) ? 1u : 0u;
      if (r < needIn) ekG[cGT + r] = ve;
    }
    for (unsigned int r = 2000u + tid; r < 2048u; r += 256)
      ekG[r] = (unsigned long long)(unsigned int)(~r);
  } else {
    // level 4 (N=819): pad path -- key 0 pads below all finite logits
    const float* cls = p.cls[l] + (size_t)b * 3 * HW;
    for (int r = tid; r < 2048; r += 256) {
      if (r < N) {
        int a = r % 3, hw = r / 3;
        unsigned int key = flipf_dev(cls[a * HW + hw]);
        ekG[r] = ((unsigned long long)key << 32) |
                 (unsigned int)(~(unsigned int)r);
      } else {
        ekG[r] = (unsigned long long)(unsigned int)(~(unsigned int)r);
      }
    }
  }
}

// --- 4b. sliced counting-rank: 8 slices x 10 tasks --------------------------
__global__ void k_rank(RPNParams p) {
  int t = blockIdx.x >> 3;
  int s = blockIdx.x & 7;
  int tid = threadIdx.x;  // 256
  __shared__ unsigned long long sl[256];
  const unsigned long long* ekG = p.ekG + (size_t)t * 2048;
  sl[tid] = ekG[s * 256 + tid];
  __syncthreads();
  unsigned long long ve[8];
  unsigned int r[8];
#pragma unroll
  for (int k = 0; k < 8; k++) {
    ve[k] = ekG[k * 256 + tid];
    r[k] = 0;
  }
  for (int j = 0; j < 256; j++) {
    unsigned long long vj = sl[j];
#pragma unroll
    for (int k = 0; k < 8; k++) r[k] += (vj > ve[k]) ? 1u : 0u;
  }
  unsigned int* out = p.partialR + ((size_t)t * 8 + s) * 2048;
#pragma unroll
  for (int k = 0; k < 8; k++) out[k * 256 + tid] = r[k];
}

// --- 4c. scatter by total rank + fp64 decode --------------------------------
__global__ void k_scatter(RPNParams p) {
  int t = blockIdx.x;  // 0..9
  int l = t >> 1, b = t & 1;
  int HW = c_HW[l];
  int tid = threadIdx.x;  // 1024
  __shared__ unsigned long long srt[2048];
  const unsigned long long* ekG = p.ekG + (size_t)t * 2048;
  for (int e = tid; e < 2048; e += 1024) {
    unsigned int rk = 0;
#pragma unroll
    for (int s = 0; s < 8; s++)
      rk += p.partialR[((size_t)t * 8 + s) * 2048 + e];
    srt[rk] = ekG[e];
  }
  __syncthreads();

  const double RCLIP = fabs(log(16.0 / 1000.0));  // mmdet wh_ratio_clip
  const float* bbx = p.bbox[l] + (size_t)b * 12 * HW;
  const float* anc = p.anc[l];
  for (int r = tid; r < NPRE; r += 1024) {
    unsigned long long v = srt[r];
    unsigned int key = (unsigned int)(v >> 32);
    double* SB = p.selBoxes + ((size_t)t * NPRE + r) * 4;
    if (key == 0u) {  // pad: zero anchors/deltas -> zero box, score -1
      SB[0] = 0.0; SB[1] = 0.0; SB[2] = 0.0; SB[3] = 0.0;
      p.selScores[(size_t)t * NPRE + r] = -1.0;
    } else {
      unsigned int idx = ~(unsigned int)(v & 0xFFFFFFFFull);
      int a = (int)(idx % 3u);
      int hw = (int)(idx / 3u);
      double d0 = (double)bbx[(a * 4 + 0) * HW + hw];
      double d1 = (double)bbx[(a * 4 + 1) * HW + hw];
      double d2 = (double)bbx[(a * 4 + 2) * HW + hw];
      double d3 = (double)bbx[(a * 4 + 3) * HW + hw];
      double a0 = (double)anc[(size_t)idx * 4 + 0];
      double a1 = (double)anc[(size_t)idx * 4 + 1];
      double a2 = (double)anc[(size_t)idx * 4 + 2];
      double a3 = (double)anc[(size_t)idx * 4 + 3];
      double dw = fmin(fmax(d2, -RCLIP), RCLIP);
      double dh = fmin(fmax(d3, -RCLIP), RCLIP);
      double pw = a2 - a0, ph = a3 - a1;
      double px = (a0 + a2) * 0.5, py = (a1 + a3) * 0.5;
      double gw = pw * exp(dw), gh = ph * exp(dh);
      double gx = px + pw * d0, gy = py + ph * d1;
      double x1 = fmin(fmax(gx - 0.5 * gw, 0.0), 1344.0);
      double y1 = fmin(fmax(gy - 0.5 * gh, 0.0), 800.0);
      double x2 = fmin(fmax(gx + 0.5 * gw, 0.0), 1344.0);
      double y2 = fmin(fmax(gy + 0.5 * gh, 0.0), 800.0);
      SB[0] = x1; SB[1] = y1; SB[2] = x2; SB[3] = y2;
      float f = unflipf_dev(key);
      p.selScores[(size_t)t * NPRE + r] = 1.0 / (1.0 + exp(-(double)f));
    }
  }
}

// --- 5. IoU -> suppression bitmask (fp32 filter + fp64 fallback band) -------
// Only upper-triangle words (k >= i>>6) are written; greedy never reads a
// stale lower word in a way that affects results (see k_greedy comment).
__global__ void k_iou(RPNParams p) {
  int bx = blockIdx.x;  // 200 blocks = 20 per task
  int t = bx / 20;
  int q = bx % 20;
  __shared__ float X1[2000], Y1[2000], X2[2000], Y2[2000], AR[2000];
  const double* SB = p.selBoxes + (size_t)t * NPRE * 4;
  for (int i = threadIdx.x; i < NPRE; i += 256) {
    float x1 = (float)SB[i * 4 + 0], y1 = (float)SB[i * 4 + 1];
    float x2 = (float)SB[i * 4 + 2], y2 = (float)SB[i * 4 + 3];
    X1[i] = x1; Y1[i] = y1; X2[i] = x2; Y2[i] = y2;
    AR[i] = (x2 - x1) * (y2 - y1);
  }
  __syncthreads();
  int wave = threadIdx.x >> 6, lane = threadIdx.x & 63;
  for (int s = 0; s < 25; s++) {
    int i = q + 20 * (wave + 4 * s);  // strided: balances (2000-i) work
    float x1i = X1[i], y1i = Y1[i], x2i = X2[i], y2i = Y2[i], ai = AR[i];
    int c0 = i >> 6;
    for (int k = c0; k < 32; k++) {
      int j = k * 64 + lane;
      bool pred = false;
      if (j > i && j < NPRE) {
        float lx = fmaxf(x1i, X1[j]), ly = fmaxf(y1i, Y1[j]);
        float rx = fminf(x2i, X2[j]), ry = fminf(y2i, Y2[j]);
        float w = fmaxf(rx - lx, 0.0f), h = fmaxf(ry - ly, 0.0f);
        float inter = w * h;
        float uni = fmaxf(ai + AR[j] - inter, 1e-6f);
        float diff = inter - 0.7f * uni;
        if (fabsf(diff) > 4.0f + 1e-5f * uni) {
          pred = diff > 0.0f;  // fp32 decision provably == fp64 decision
        } else {
          double a0 = SB[i * 4 + 0], b0 = SB[i * 4 + 1];
          double a2 = SB[i * 4 + 2], b2 = SB[i * 4 + 3];
          double c0d = SB[j * 4 + 0], d0 = SB[j * 4 + 1];
          double c2 = SB[j * 4 + 2], d2 = SB[j * 4 + 3];
          double dai = (a2 - a0) * (b2 - b0);
          double daj = (c2 - c0d) * (d2 - d0);
          double lxd = fmax(a0, c0d), lyd = fmax(b0, d0);
          double rxd = fmin(a2, c2), ryd = fmin(b2, d2);
          double wd = fmax(rxd - lxd, 0.0), hd = fmax(ryd - lyd, 0.0);
          double interd = wd * hd;
          double unid = fmax(dai + daj - interd, 1e-6);
          pred = (interd / unid) > 0.7;
        }
      }
      unsigned long long word = __ballot(pred);
      if (lane == 0) p.mask[((size_t)t * NPRE + i) * 32 + k] = word;
    }
  }
}

// --- 6. greedy NMS: producer/consumer wave specialization, 1 block/task -----
// Wave 1 (producer): streams 16-row mask groups (4 KB contiguous) into a
//   12-slot LDS ring; publishes `prog` after __threadfence_block().
// Wave 0 (consumer): lane j<32 holds suppression word j. Per group (all 16
//   rows share owner chunk c=g/4): owner lane runs the 16-step serial
//   closure locally; one 32-bit shfl broadcasts kept-row mask; other lanes
//   OR branchlessly. Poisoned lower-triangle words only ever OR into supp
//   words whose keep is already final (chunk j fully processed before any
//   row with chunk > j is applied), so they cannot affect results.
#define RING 12
__global__ __launch_bounds__(128) void k_greedy(RPNParams p) {
  int t = blockIdx.x;
  int tid = threadIdx.x;
  __shared__ unsigned long long ring[RING * 512];  // 12 * 4 KB = 48 KB
  __shared__ int prog_s, cons_s;
  volatile int* prog = &prog_s;
  volatile int* cons = &cons_s;
  const unsigned long long* MK = p.mask + (size_t)t * NPRE * 32;
  if (tid == 0) { prog_s = 0; cons_s = 0; }
  __syncthreads();

  if (tid >= 64) {
    // ---------------- producer wave ----------------
    int lane = tid - 64;
    for (int g = 0; g < 125; g++) {
      while (g - *cons >= RING) __builtin_amdgcn_s_sleep(8);
      unsigned long long v[8];
#pragma unroll
      for (int k = 0; k < 8; k++)
        v[k] = MK[(size_t)g * 512 + k * 64 + lane];
      int slot = g % RING;
#pragma unroll
      for (int k = 0; k < 8; k++)
        ring[slot * 512 + k * 64 + lane] = v[k];
      __threadfence_block();  // data visible before publish
      if (lane == 0) *prog = g + 1;
    }
  } else {
    // ---------------- consumer wave ----------------
    int lane = tid;  // 0..63
    unsigned long long supp = 0ull, keep = 0ull;
    for (int g = 0; g < 125; g++) {
      while (*prog < g + 1) __builtin_amdgcn_s_sleep(2);
      int slot = g % RING;
      int c = g >> 2;  // owner chunk (16 rows per group, 4 groups per chunk)
      unsigned long long rv[16];
#pragma unroll
      for (int r = 0; r < 16; r++)
        rv[r] = ring[slot * 512 + r * 32 + (lane & 31)];
      unsigned int kg = 0;
      if (lane == c) {
        unsigned long long s = supp;
        int base = (g & 3) * 16;  // bit offset within the 64-bit chunk word
#pragma unroll
        for (int r = 0; r < 16; r++) {
          int b = base + r;
          if (!((s >> b) & 1ull)) {
            kg |= 1u << r;
            s |= rv[r];
          }
        }
        supp = s;
        keep |= (unsigned long long)kg << base;
      }
      kg = (unsigned int)__shfl((int)kg, c);
      if (lane != c) {
#pragma unroll
        for (int r = 0; r < 16; r++)
          supp |= ((kg >> r) & 1u) ? rv[r] : 0ull;
      }
      __threadfence_block();  // rv reads retired before freeing slot
      if (lane == 63) *cons = g + 1;
    }
    if (lane < 32) p.keeps[(size_t)t * 32 + lane] = keep;
  }
}

// --- 7. per-task re-rank: kept(+score) first (idx order), then -1 group -----
__global__ void k_post(RPNParams p) {
  int t = blockIdx.x;
  __shared__ unsigned long long kw[32], aw[32], bw[32];
  __shared__ unsigned int prefA[33], prefB[33];
  int tid = threadIdx.x;  // 256
  if (tid < 32) kw[tid] = p.keeps[(size_t)t * 32 + tid];
  __syncthreads();
  int wave = tid >> 6, lane = tid & 63;
  for (int ch = wave; ch < 32; ch += 4) {
    int i = ch * 64 + lane;
    bool inr = i < NPRE;
    bool kb = inr && ((kw[ch] >> lane) & 1ull);
    bool A = kb && (inr ? (p.selScores[(size_t)t * NPRE + i] > -0.5) : false);
    bool B = inr && !A;
    unsigned long long wa = __ballot(A);
    unsigned long long wb = __ballot(B);
    if (lane == 0) { aw[ch] = wa; bw[ch] = wb; }
  }
  __syncthreads();
  if (tid == 0) {
    unsigned int ca = 0, cb = 0;
    for (int w = 0; w < 32; w++) {
      prefA[w] = ca; ca += __popcll(aw[w]);
      prefB[w] = cb; cb += __popcll(bw[w]);
    }
    prefA[32] = ca; prefB[32] = cb;
  }
  __syncthreads();
  unsigned int KA = prefA[32];
  for (int i = tid; i < NPRE; i += 256) {
    int w = i >> 6, bpos = i & 63;
    unsigned long long below = (bpos == 0) ? 0ull : (~0ull >> (64 - bpos));
    bool kb = (kw[w] >> bpos) & 1ull;
    double s = p.selScores[(size_t)t * NPRE + i];
    bool A = kb && (s > -0.5);
    unsigned int slot;
    double outs;
    if (A) {
      slot = prefA[w] + (unsigned int)__popcll(aw[w] & below);
      outs = s;
    } else {
      slot = KA + prefB[w] + (unsigned int)__popcll(bw[w] & below);
      outs = -1.0;
    }
    if (slot < NPOST) {
      p.postScores[(size_t)t * NPOST + slot] = outs;
      const double* SB = p.selBoxes + ((size_t)t * NPRE + i) * 4;
      float* PB = p.postBoxes + ((size_t)t * NPOST + slot) * 4;
      PB[0] = (float)SB[0]; PB[1] = (float)SB[1];
      PB[2] = (float)SB[2]; PB[3] = (float)SB[3];
    }
  }
}

// --- 8a. final cross-level top-1000: sliced counting-rank -------------------
__global__ void k_finalA(RPNParams p) {
  int b = blockIdx.x >> 3;
  int s = blockIdx.x & 7;
  int j0 = s * 625;
  __shared__ unsigned long long kj[625];
  int tid = threadIdx.x;  // 1024
  for (int j = tid; j < 625; j += 1024) {
    int e = j0 + j;
    int l = e / 1000, slot = e % 1000;
    int t = l * 2 + b;
    kj[j] = flip64_dev(p.postScores[(size_t)t * NPOST + slot]);
  }
  __syncthreads();
  for (int e = tid; e < 5000; e += 1024) {
    int l = e / 1000, slot = e % 1000;
    int t = l * 2 + b;
    unsigned long long ke = flip64_dev(p.postScores[(size_t)t * NPOST + slot]);
    unsigned int r = 0;
    for (int j = 0; j < 625; j++) {
      unsigned long long v = kj[j];
      int jg = j0 + j;
      r += (v > ke || (v == ke && jg < e)) ? 1u : 0u;
    }
    p.partial[((size_t)b * 8 + s) * 5000 + e] = r;
  }
}

// --- 8b. reduce ranks, gather output boxes ----------------------------------
__global__ void k_finalB(RPNParams p) {
  int b = blockIdx.x;
  int tid = threadIdx.x;
  for (int e = tid; e < 5000; e += 1024) {
    unsigned int r = 0;
    for (int s = 0; s < 8; s++) r += p.partial[((size_t)b * 8 + s) * 5000 + e];
    if (r < NPOST) {
      int l = e / 1000, slot = e % 1000;
      int t = l * 2 + b;
      const float* PB = p.postBoxes + ((size_t)t * NPOST + slot) * 4;
      float* O = p.out + ((size_t)b * NPOST + r) * 4;
      O[0] = PB[0]; O[1] = PB[1]; O[2] = PB[2]; O[3] = PB[3];
    }
  }
}

extern "C" void kernel_launch(void* const* d_in, const int* in_sizes, int n_in,
                              void* d_out, int out_size, void* d_ws,
                              size_t ws_size, hipStream_t stream) {
  RPNParams p;
  bool interleaved = (n_in >= 2) && (in_sizes[1] == 4 * in_sizes[0]);
  for (int l = 0; l < 5; l++) {
    if (interleaved) {
      p.cls[l]  = (const float*)d_in[3 * l + 0];
      p.bbox[l] = (const float*)d_in[3 * l + 1];
      p.anc[l]  = (const float*)d_in[3 * l + 2];
    } else {
      p.cls[l]  = (const float*)d_in[l];
      p.bbox[l] = (const float*)d_in[5 + l];
      p.anc[l]  = (const float*)d_in[10 + l];
    }
  }
  char* w = (char*)d_ws;
  size_t off = 0;
  auto alloc = [&](size_t bytes) {
    off = (off + 255) & ~(size_t)255;
    void* r = w + off;
    off += bytes;
    return r;
  };
  p.hist      = (unsigned int*)alloc((size_t)10 * 65536 * 4);
  p.mainCount = (unsigned int*)alloc(10 * 4);
  p.candCount = (unsigned int*)alloc(10 * 4);
  size_t zbytes = off;  // zeroed region: hist + atomic counters
  p.Bstar      = (unsigned int*)alloc(10 * 4);
  p.mainEK     = (unsigned long long*)alloc((size_t)10 * 2048 * 8);
  p.candEK     = (unsigned long long*)alloc((size_t)10 * 8192 * 8);
  p.ekG        = (unsigned long long*)alloc((size_t)10 * 2048 * 8);
  p.partialR   = (unsigned int*)alloc((size_t)10 * 8 * 2048 * 4);
  p.selBoxes   = (double*)alloc((size_t)10 * NPRE * 4 * 8);
  p.selScores  = (double*)alloc((size_t)10 * NPRE * 8);
  p.mask       = (unsigned long long*)alloc((size_t)10 * NPRE * 32 * 8);
  p.keeps      = (unsigned long long*)alloc((size_t)10 * 32 * 8);
  p.postScores = (double*)alloc((size_t)10 * NPOST * 8);
  p.postBoxes  = (float*)alloc((size_t)10 * NPOST * 4 * 4);
  p.partial    = (unsigned int*)alloc((size_t)16 * 5000 * 4);
  p.out = (float*)d_out;
  (void)ws_size; (void)out_size;

  hipMemsetAsync(d_ws, 0, zbytes, stream);
  k_hist<<<dim3(136), dim3(1024), 0, stream>>>(p);
  k_find<<<dim3(8), dim3(1024), 0, stream>>>(p);
  k_compact<<<dim3(136), dim3(1024), 0, stream>>>(p);
  k_fill<<<dim3(10), dim3(256), 0, stream>>>(p);
  k_rank<<<dim3(80), dim3(256), 0, stream>>>(p);
  k_scatter<<<dim3(10), dim3(1024), 0, stream>>>(p);
  k_iou<<<dim3(200), dim3(256), 0, stream>>>(p);
  k_greedy<<<dim3(10), dim3(128), 0, stream>>>(p);
  k_post<<<dim3(10), dim3(256), 0, stream>>>(p);
  k_finalA<<<dim3(16), dim3(1024), 0, stream>>>(p);
  k_finalB<<<dim3(2), dim3(1024), 0, stream>>>(p);
}

// Round 5
// 606.493 us; speedup vs baseline: 1.7470x; 1.0806x over previous
//
#include <hip/hip_runtime.h>
#include <cmath>

// ---------------------------------------------------------------------------
// RPN head post-processing (mmdet GetBboxes-style), exact-semantics HIP port.
//
// Correctness: ordering-critical math fp64-exact (sigmoid, delta2bbox) or
// fp64-equivalent (IoU: fp32 filter + fp64 fallback band); top-k ordering on
// raw fp32 logit bits (monotone == fp64 sigmoid order; ties -> lower index).
//
// R1-R3 lesson: serial greedy scan cannot hold a register prefetch pipeline
// (spill -> scratch chain). R4: producer/consumer wave specialization for
// greedy (passed, left top-5). R5: k_iou was latency-bound (VALUBusy 13%,
// occ 6%: 410 serial k-iters/wave, each a ~300cy dependent LDS chain).
// Now 4 consecutive rows share each column-word load: 5 LDS reads feed
// 4 independent IoUs (4x ILP, 4x fewer iterations), 25 blocks/task.
// ---------------------------------------------------------------------------

#define NPRE 2000
#define NPOST 1000

static __device__ __forceinline__ unsigned int flipf_dev(float f) {
  unsigned int u = __float_as_uint(f);
  return (u & 0x80000000u) ? ~u : (u | 0x80000000u);
}
static __device__ __forceinline__ float unflipf_dev(unsigned int k) {
  unsigned int u = (k & 0x80000000u) ? (k ^ 0x80000000u) : ~k;
  return __uint_as_float(u);
}
static __device__ __forceinline__ unsigned long long flip64_dev(double d) {
  unsigned long long u = (unsigned long long)__double_as_longlong(d);
  return (u & 0x8000000000000000ull) ? ~u : (u | 0x8000000000000000ull);
}

struct RPNParams {
  const float* cls[5];
  const float* bbox[5];
  const float* anc[5];
  unsigned int* hist;          // [10][65536]
  unsigned int* mainCount;     // [10]
  unsigned int* candCount;     // [10]
  unsigned int* Bstar;         // [10]
  unsigned long long* mainEK;  // [10][2048]  packed (key<<32)|~idx
  unsigned long long* candEK;  // [10][8192]
  unsigned long long* ekG;     // [10][2048]  assembled top-2000 (+pads)
  unsigned int* partialR;      // [10][8][2048] sliced ranks
  double* selBoxes;            // [10][2000][4]
  double* selScores;           // [10][2000]
  unsigned long long* mask;    // [10][2000][32]
  unsigned long long* keeps;   // [10][32]
  double* postScores;          // [10][1000]
  float* postBoxes;            // [10][1000][4]
  unsigned int* partial;       // [16][5000]
  float* out;                  // [2][1000][4]
};

__device__ __constant__ int c_NL[5]  = {201600, 50400, 12600, 3150, 819};
__device__ __constant__ int c_HW[5]  = {67200, 16800, 4200, 1050, 273};
__device__ __constant__ int c_BPT[8] = {50, 50, 13, 13, 4, 4, 1, 1};

static __device__ __forceinline__ void map_block(int bx, int& t, int& chunk) {
  int start = 0;
  t = 0;
  for (int k = 0; k < 8; k++) {
    if (bx < start + c_BPT[k]) { t = k; break; }
    start += c_BPT[k];
  }
  chunk = bx - start;
}

// --- 1. per-task 16-bit-bucket histogram of flipped logit keys --------------
__global__ void k_hist(RPNParams p) {
  int t, chunk;
  map_block(blockIdx.x, t, chunk);
  int l = t >> 1, b = t & 1;
  int N = c_NL[l], HW = c_HW[l];
  const float* cls = p.cls[l] + (size_t)b * 3 * HW;
  unsigned int* hist = p.hist + (size_t)t * 65536;
  int base = chunk * 4096 + threadIdx.x;
  for (int k = 0; k < 4; k++) {
    int n = base + k * 1024;
    if (n < N) {
      int a = n % 3, hw = n / 3;
      unsigned int key = flipf_dev(cls[a * HW + hw]);
      atomicAdd(&hist[key >> 16], 1u);
    }
  }
}

// --- 2. find threshold bucket B* per task -----------------------------------
__global__ void k_find(RPNParams p) {
  int t = blockIdx.x;  // 0..7
  unsigned int* hist = p.hist + (size_t)t * 65536;
  __shared__ unsigned int S[1024];
  __shared__ int gsel;
  __shared__ unsigned int baseAbove;
  int g = threadIdx.x;
  unsigned int s = 0;
  for (int j = 0; j < 64; j++) s += hist[g * 64 + j];
  S[g] = s;
  __syncthreads();
  for (int off = 1; off < 1024; off <<= 1) {
    unsigned int add = (g + off < 1024) ? S[g + off] : 0u;
    __syncthreads();
    S[g] += add;
    __syncthreads();
  }
  const unsigned int need = NPRE;
  if (S[g] >= need && (g == 1023 || S[g + 1] < need)) {
    gsel = g;
    baseAbove = (g == 1023) ? 0u : S[g + 1];
  }
  __syncthreads();
  if (threadIdx.x == 0) {
    int gg = gsel;
    unsigned int c = baseAbove;
    int bstar = gg * 64;
    for (int bb = gg * 64 + 63; bb >= gg * 64; bb--) {
      c += hist[bb];
      if (c >= need) { bstar = bb; break; }
    }
    p.Bstar[t] = (unsigned int)bstar;
  }
}

// --- 3. compaction: above-bucket -> main, == bucket -> cand -----------------
__global__ void k_compact(RPNParams p) {
  int t, chunk;
  map_block(blockIdx.x, t, chunk);
  int l = t >> 1, b = t & 1;
  int N = c_NL[l], HW = c_HW[l];
  const float* cls = p.cls[l] + (size_t)b * 3 * HW;
  unsigned int Bs = p.Bstar[t];
  int base = chunk * 4096 + threadIdx.x;
  for (int k = 0; k < 4; k++) {
    int n = base + k * 1024;
    if (n < N) {
      int a = n % 3, hw = n / 3;
      unsigned int key = flipf_dev(cls[a * HW + hw]);
      unsigned int hi = key >> 16;
      unsigned long long ek =
          ((unsigned long long)key << 32) | (unsigned int)(~(unsigned int)n);
      if (hi > Bs) {
        unsigned int pos = atomicAdd(&p.mainCount[t], 1u);
        if (pos < 2048u) p.mainEK[(size_t)t * 2048 + pos] = ek;
      } else if (hi == Bs) {
        unsigned int pos = atomicAdd(&p.candCount[t], 1u);
        if (pos < 8192u) p.candEK[(size_t)t * 8192 + pos] = ek;
      }
    }
  }
}

// --- 4a. fill ekG[t][2048]: exact top-2000 keys + pads ----------------------
__global__ void k_fill(RPNParams p) {
  int t = blockIdx.x;  // 0..9
  int l = t >> 1, b = t & 1;
  int N = c_NL[l], HW = c_HW[l];
  int tid = threadIdx.x;  // 256
  unsigned long long* ekG = p.ekG + (size_t)t * 2048;
  if (N >= NPRE) {
    unsigned int cGT = min(p.mainCount[t], 2000u);
    unsigned int nC = min(p.candCount[t], 8192u);
    unsigned int needIn = 2000u - cGT;
    for (unsigned int m = tid; m < cGT; m += 256)
      ekG[m] = p.mainEK[(size_t)t * 2048 + m];
    const unsigned long long* cek = p.candEK + (size_t)t * 8192;
    for (unsigned int e = tid; e < nC; e += 256) {
      unsigned long long ve = cek[e];
      unsigned int r = 0;
      for (unsigned int j = 0; j < nC; j++) r += (cek[j] > ve) ? 1u : 0u;
      if (r < needIn) ekG[cGT + r] = ve;
    }
    for (unsigned int r = 2000u + tid; r < 2048u; r += 256)
      ekG[r] = (unsigned long long)(unsigned int)(~r);
  } else {
    // level 4 (N=819): pad path -- key 0 pads below all finite logits
    const float* cls = p.cls[l] + (size_t)b * 3 * HW;
    for (int r = tid; r < 2048; r += 256) {
      if (r < N) {
        int a = r % 3, hw = r / 3;
        unsigned int key = flipf_dev(cls[a * HW + hw]);
        ekG[r] = ((unsigned long long)key << 32) |
                 (unsigned int)(~(unsigned int)r);
      } else {
        ekG[r] = (unsigned long long)(unsigned int)(~(unsigned int)r);
      }
    }
  }
}

// --- 4b. sliced counting-rank: 8 slices x 10 tasks --------------------------
__global__ void k_rank(RPNParams p) {
  int t = blockIdx.x >> 3;
  int s = blockIdx.x & 7;
  int tid = threadIdx.x;  // 256
  __shared__ unsigned long long sl[256];
  const unsigned long long* ekG = p.ekG + (size_t)t * 2048;
  sl[tid] = ekG[s * 256 + tid];
  __syncthreads();
  unsigned long long ve[8];
  unsigned int r[8];
#pragma unroll
  for (int k = 0; k < 8; k++) {
    ve[k] = ekG[k * 256 + tid];
    r[k] = 0;
  }
  for (int j = 0; j < 256; j++) {
    unsigned long long vj = sl[j];
#pragma unroll
    for (int k = 0; k < 8; k++) r[k] += (vj > ve[k]) ? 1u : 0u;
  }
  unsigned int* out = p.partialR + ((size_t)t * 8 + s) * 2048;
#pragma unroll
  for (int k = 0; k < 8; k++) out[k * 256 + tid] = r[k];
}

// --- 4c. scatter by total rank + fp64 decode --------------------------------
__global__ void k_scatter(RPNParams p) {
  int t = blockIdx.x;  // 0..9
  int l = t >> 1, b = t & 1;
  int HW = c_HW[l];
  int tid = threadIdx.x;  // 1024
  __shared__ unsigned long long srt[2048];
  const unsigned long long* ekG = p.ekG + (size_t)t * 2048;
  for (int e = tid; e < 2048; e += 1024) {
    unsigned int rk = 0;
#pragma unroll
    for (int s = 0; s < 8; s++)
      rk += p.partialR[((size_t)t * 8 + s) * 2048 + e];
    srt[rk] = ekG[e];
  }
  __syncthreads();

  const double RCLIP = fabs(log(16.0 / 1000.0));  // mmdet wh_ratio_clip
  const float* bbx = p.bbox[l] + (size_t)b * 12 * HW;
  const float* anc = p.anc[l];
  for (int r = tid; r < NPRE; r += 1024) {
    unsigned long long v = srt[r];
    unsigned int key = (unsigned int)(v >> 32);
    double* SB = p.selBoxes + ((size_t)t * NPRE + r) * 4;
    if (key == 0u) {  // pad: zero anchors/deltas -> zero box, score -1
      SB[0] = 0.0; SB[1] = 0.0; SB[2] = 0.0; SB[3] = 0.0;
      p.selScores[(size_t)t * NPRE + r] = -1.0;
    } else {
      unsigned int idx = ~(unsigned int)(v & 0xFFFFFFFFull);
      int a = (int)(idx % 3u);
      int hw = (int)(idx / 3u);
      double d0 = (double)bbx[(a * 4 + 0) * HW + hw];
      double d1 = (double)bbx[(a * 4 + 1) * HW + hw];
      double d2 = (double)bbx[(a * 4 + 2) * HW + hw];
      double d3 = (double)bbx[(a * 4 + 3) * HW + hw];
      double a0 = (double)anc[(size_t)idx * 4 + 0];
      double a1 = (double)anc[(size_t)idx * 4 + 1];
      double a2 = (double)anc[(size_t)idx * 4 + 2];
      double a3 = (double)anc[(size_t)idx * 4 + 3];
      double dw = fmin(fmax(d2, -RCLIP), RCLIP);
      double dh = fmin(fmax(d3, -RCLIP), RCLIP);
      double pw = a2 - a0, ph = a3 - a1;
      double px = (a0 + a2) * 0.5, py = (a1 + a3) * 0.5;
      double gw = pw * exp(dw), gh = ph * exp(dh);
      double gx = px + pw * d0, gy = py + ph * d1;
      double x1 = fmin(fmax(gx - 0.5 * gw, 0.0), 1344.0);
      double y1 = fmin(fmax(gy - 0.5 * gh, 0.0), 800.0);
      double x2 = fmin(fmax(gx + 0.5 * gw, 0.0), 1344.0);
      double y2 = fmin(fmax(gy + 0.5 * gh, 0.0), 800.0);
      SB[0] = x1; SB[1] = y1; SB[2] = x2; SB[3] = y2;
      float f = unflipf_dev(key);
      p.selScores[(size_t)t * NPRE + r] = 1.0 / (1.0 + exp(-(double)f));
    }
  }
}

// --- 5. IoU -> suppression bitmask. 4 rows share each column load. ----------
// Group g = rows 4g..4g+3 (same k range, c0 differs <=1; j>i guard exact).
// Words with k < row's own chunk are written as 0 -- harmless to k_greedy.
// fp32 filter + fp64 fallback only inside conservative band of the 0.7
// boundary (fp32 error bound << band => predicate identical to fp64).
__global__ void k_iou(RPNParams p) {
  int bx = blockIdx.x;  // 250 blocks = 25 per task
  int t = bx / 25;
  int q = bx % 25;
  __shared__ float X1[2048], Y1[2048], X2[2048], Y2[2048], AR[2048];
  const double* SB = p.selBoxes + (size_t)t * NPRE * 4;
  for (int i = threadIdx.x; i < 2048; i += 256) {
    float x1 = 0.f, y1 = 0.f, x2 = 0.f, y2 = 0.f;
    if (i < NPRE) {
      x1 = (float)SB[i * 4 + 0]; y1 = (float)SB[i * 4 + 1];
      x2 = (float)SB[i * 4 + 2]; y2 = (float)SB[i * 4 + 3];
    }
    X1[i] = x1; Y1[i] = y1; X2[i] = x2; Y2[i] = y2;
    AR[i] = (x2 - x1) * (y2 - y1);
  }
  __syncthreads();
  int wave = threadIdx.x >> 6, lane = threadIdx.x & 63;
  for (int s = 0; s < 5; s++) {
    int g = q + 25 * (wave + 4 * s);  // [0,500), strided for balance
    int i0 = g * 4;
    float x1i[4], y1i[4], x2i[4], y2i[4], ai[4];
#pragma unroll
    for (int r = 0; r < 4; r++) {
      int i = i0 + r;
      x1i[r] = X1[i]; y1i[r] = Y1[i]; x2i[r] = X2[i]; y2i[r] = Y2[i];
      ai[r] = AR[i];
    }
    int c0 = i0 >> 6;
    for (int k = c0; k < 32; k++) {
      int j = k * 64 + lane;
      float xj1 = X1[j], yj1 = Y1[j], xj2 = X2[j], yj2 = Y2[j], arj = AR[j];
      bool jin = j < NPRE;
#pragma unroll
      for (int r = 0; r < 4; r++) {
        int i = i0 + r;
        bool valid = jin && (j > i);
        float lx = fmaxf(x1i[r], xj1), ly = fmaxf(y1i[r], yj1);
        float rx = fminf(x2i[r], xj2), ry = fminf(y2i[r], yj2);
        float w = fmaxf(rx - lx, 0.0f), h = fmaxf(ry - ly, 0.0f);
        float inter = w * h;
        float uni = fmaxf(ai[r] + arj - inter, 1e-6f);
        float diff = inter - 0.7f * uni;
        bool pred = (diff > 0.0f) && valid;
        if (valid && fabsf(diff) <= 4.0f + 1e-5f * uni) {
          // exact fp64 fallback (rare: only near the 0.7 boundary)
          double a0 = SB[i * 4 + 0], b0 = SB[i * 4 + 1];
          double a2 = SB[i * 4 + 2], b2 = SB[i * 4 + 3];
          double c0d = SB[j * 4 + 0], d0 = SB[j * 4 + 1];
          double c2 = SB[j * 4 + 2], d2 = SB[j * 4 + 3];
          double dai = (a2 - a0) * (b2 - b0);
          double daj = (c2 - c0d) * (d2 - d0);
          double lxd = fmax(a0, c0d), lyd = fmax(b0, d0);
          double rxd = fmin(a2, c2), ryd = fmin(b2, d2);
          double wd = fmax(rxd - lxd, 0.0), hd = fmax(ryd - lyd, 0.0);
          double interd = wd * hd;
          double unid = fmax(dai + daj - interd, 1e-6);
          pred = (interd / unid) > 0.7;
        }
        unsigned long long word = __ballot(pred);
        if (lane == 0) p.mask[((size_t)t * NPRE + i) * 32 + k] = word;
      }
    }
  }
}

// --- 6. greedy NMS: producer/consumer wave specialization, 1 block/task -----
// Wave 1 (producer): streams 16-row mask groups (4 KB contiguous) into a
//   12-slot LDS ring; publishes `prog` after __threadfence_block().
// Wave 0 (consumer): lane j<32 holds suppression word j. Per group (all 16
//   rows share owner chunk c=g/4): owner lane runs the 16-step serial
//   closure locally; one 32-bit shfl broadcasts kept-row mask; other lanes
//   OR branchlessly. Poisoned lower-triangle words only ever OR into supp
//   words whose keep is already final, so they cannot affect results.
#define RING 12
__global__ __launch_bounds__(128) void k_greedy(RPNParams p) {
  int t = blockIdx.x;
  int tid = threadIdx.x;
  __shared__ unsigned long long ring[RING * 512];  // 12 * 4 KB = 48 KB
  __shared__ int prog_s, cons_s;
  volatile int* prog = &prog_s;
  volatile int* cons = &cons_s;
  const unsigned long long* MK = p.mask + (size_t)t * NPRE * 32;
  if (tid == 0) { prog_s = 0; cons_s = 0; }
  __syncthreads();

  if (tid >= 64) {
    // ---------------- producer wave ----------------
    int lane = tid - 64;
    for (int g = 0; g < 125; g++) {
      while (g - *cons >= RING) __builtin_amdgcn_s_sleep(8);
      unsigned long long v[8];
#pragma unroll
      for (int k = 0; k < 8; k++)
        v[k] = MK[(size_t)g * 512 + k * 64 + lane];
      int slot = g % RING;
#pragma unroll
      for (int k = 0; k < 8; k++)
        ring[slot * 512 + k * 64 + lane] = v[k];
      __threadfence_block();  // data visible before publish
      if (lane == 0) *prog = g + 1;
    }
  } else {
    // ---------------- consumer wave ----------------
    int lane = tid;  // 0..63
    unsigned long long supp = 0ull, keep = 0ull;
    for (int g = 0; g < 125; g++) {
      while (*prog < g + 1) __builtin_amdgcn_s_sleep(2);
      int slot = g % RING;
      int c = g >> 2;  // owner chunk (16 rows per group, 4 groups per chunk)
      unsigned long long rv[16];
#pragma unroll
      for (int r = 0; r < 16; r++)
        rv[r] = ring[slot * 512 + r * 32 + (lane & 31)];
      unsigned int kg = 0;
      if (lane == c) {
        unsigned long long s = supp;
        int base = (g & 3) * 16;  // bit offset within the 64-bit chunk word
#pragma unroll
        for (int r = 0; r < 16; r++) {
          int b = base + r;
          if (!((s >> b) & 1ull)) {
            kg |= 1u << r;
            s |= rv[r];
          }
        }
        supp = s;
        keep |= (unsigned long long)kg << base;
      }
      kg = (unsigned int)__shfl((int)kg, c);
      if (lane != c) {
#pragma unroll
        for (int r = 0; r < 16; r++)
          supp |= ((kg >> r) & 1u) ? rv[r] : 0ull;
      }
      __threadfence_block();  // rv reads retired before freeing slot
      if (lane == 63) *cons = g + 1;
    }
    if (lane < 32) p.keeps[(size_t)t * 32 + lane] = keep;
  }
}

// --- 7. per-task re-rank: kept(+score) first (idx order), then -1 group -----
__global__ void k_post(RPNParams p) {
  int t = blockIdx.x;
  __shared__ unsigned long long kw[32], aw[32], bw[32];
  __shared__ unsigned int prefA[33], prefB[33];
  int tid = threadIdx.x;  // 256
  if (tid < 32) kw[tid] = p.keeps[(size_t)t * 32 + tid];
  __syncthreads();
  int wave = tid >> 6, lane = tid & 63;
  for (int ch = wave; ch < 32; ch += 4) {
    int i = ch * 64 + lane;
    bool inr = i < NPRE;
    bool kb = inr && ((kw[ch] >> lane) & 1ull);
    bool A = kb && (inr ? (p.selScores[(size_t)t * NPRE + i] > -0.5) : false);
    bool B = inr && !A;
    unsigned long long wa = __ballot(A);
    unsigned long long wb = __ballot(B);
    if (lane == 0) { aw[ch] = wa; bw[ch] = wb; }
  }
  __syncthreads();
  if (tid == 0) {
    unsigned int ca = 0, cb = 0;
    for (int w = 0; w < 32; w++) {
      prefA[w] = ca; ca += __popcll(aw[w]);
      prefB[w] = cb; cb += __popcll(bw[w]);
    }
    prefA[32] = ca; prefB[32] = cb;
  }
  __syncthreads();
  unsigned int KA = prefA[32];
  for (int i = tid; i < NPRE; i += 256) {
    int w = i >> 6, bpos = i & 63;
    unsigned long long below = (bpos == 0) ? 0ull : (~0ull >> (64 - bpos));
    bool kb = (kw[w] >> bpos) & 1ull;
    double s = p.selScores[(size_t)t * NPRE + i];
    bool A = kb && (s > -0.5);
    unsigned int slot;
    double outs;
    if (A) {
      slot = prefA[w] + (unsigned int)__popcll(aw[w] & below);
      outs = s;
    } else {
      slot = KA + prefB[w] + (unsigned int)__popcll(bw[w] & below);
      outs = -1.0;
    }
    if (slot < NPOST) {
      p.postScores[(size_t)t * NPOST + slot] = outs;
      const double* SB = p.selBoxes + ((size_t)t * NPRE + i) * 4;
      float* PB = p.postBoxes + ((size_t)t * NPOST + slot) * 4;
      PB[0] = (float)SB[0]; PB[1] = (float)SB[1];
      PB[2] = (float)SB[2]; PB[3] = (float)SB[3];
    }
  }
}

// --- 8a. final cross-level top-1000: sliced counting-rank -------------------
__global__ void k_finalA(RPNParams p) {
  int b = blockIdx.x >> 3;
  int s = blockIdx.x & 7;
  int j0 = s * 625;
  __shared__ unsigned long long kj[625];
  int tid = threadIdx.x;  // 1024
  for (int j = tid; j < 625; j += 1024) {
    int e = j0 + j;
    int l = e / 1000, slot = e % 1000;
    int t = l * 2 + b;
    kj[j] = flip64_dev(p.postScores[(size_t)t * NPOST + slot]);
  }
  __syncthreads();
  for (int e = tid; e < 5000; e += 1024) {
    int l = e / 1000, slot = e % 1000;
    int t = l * 2 + b;
    unsigned long long ke = flip64_dev(p.postScores[(size_t)t * NPOST + slot]);
    unsigned int r = 0;
    for (int j = 0; j < 625; j++) {
      unsigned long long v = kj[j];
      int jg = j0 + j;
      r += (v > ke || (v == ke && jg < e)) ? 1u : 0u;
    }
    p.partial[((size_t)b * 8 + s) * 5000 + e] = r;
  }
}

// --- 8b. reduce ranks, gather output boxes ----------------------------------
__global__ void k_finalB(RPNParams p) {
  int b = blockIdx.x;
  int tid = threadIdx.x;
  for (int e = tid; e < 5000; e += 1024) {
    unsigned int r = 0;
    for (int s = 0; s < 8; s++) r += p.partial[((size_t)b * 8 + s) * 5000 + e];
    if (r < NPOST) {
      int l = e / 1000, slot = e % 1000;
      int t = l * 2 + b;
      const float* PB = p.postBoxes + ((size_t)t * NPOST + slot) * 4;
      float* O = p.out + ((size_t)b * NPOST + r) * 4;
      O[0] = PB[0]; O[1] = PB[1]; O[2] = PB[2]; O[3] = PB[3];
    }
  }
}

extern "C" void kernel_launch(void* const* d_in, const int* in_sizes, int n_in,
                              void* d_out, int out_size, void* d_ws,
                              size_t ws_size, hipStream_t stream) {
  RPNParams p;
  bool interleaved = (n_in >= 2) && (in_sizes[1] == 4 * in_sizes[0]);
  for (int l = 0; l < 5; l++) {
    if (interleaved) {
      p.cls[l]  = (const float*)d_in[3 * l + 0];
      p.bbox[l] = (const float*)d_in[3 * l + 1];
      p.anc[l]  = (const float*)d_in[3 * l + 2];
    } else {
      p.cls[l]  = (const float*)d_in[l];
      p.bbox[l] = (const float*)d_in[5 + l];
      p.anc[l]  = (const float*)d_in[10 + l];
    }
  }
  char* w = (char*)d_ws;
  size_t off = 0;
  auto alloc = [&](size_t bytes) {
    off = (off + 255) & ~(size_t)255;
    void* r = w + off;
    off += bytes;
    return r;
  };
  p.hist      = (unsigned int*)alloc((size_t)10 * 65536 * 4);
  p.mainCount = (unsigned int*)alloc(10 * 4);
  p.candCount = (unsigned int*)alloc(10 * 4);
  size_t zbytes = off;  // zeroed region: hist + atomic counters
  p.Bstar      = (unsigned int*)alloc(10 * 4);
  p.mainEK     = (unsigned long long*)alloc((size_t)10 * 2048 * 8);
  p.candEK     = (unsigned long long*)alloc((size_t)10 * 8192 * 8);
  p.ekG        = (unsigned long long*)alloc((size_t)10 * 2048 * 8);
  p.partialR   = (unsigned int*)alloc((size_t)10 * 8 * 2048 * 4);
  p.selBoxes   = (double*)alloc((size_t)10 * NPRE * 4 * 8);
  p.selScores  = (double*)alloc((size_t)10 * NPRE * 8);
  p.mask       = (unsigned long long*)alloc((size_t)10 * NPRE * 32 * 8);
  p.keeps      = (unsigned long long*)alloc((size_t)10 * 32 * 8);
  p.postScores = (double*)alloc((size_t)10 * NPOST * 8);
  p.postBoxes  = (float*)alloc((size_t)10 * NPOST * 4 * 4);
  p.partial    = (unsigned int*)alloc((size_t)16 * 5000 * 4);
  p.out = (float*)d_out;
  (void)ws_size; (void)out_size;

  hipMemsetAsync(d_ws, 0, zbytes, stream);
  k_hist<<<dim3(136), dim3(1024), 0, stream>>>(p);
  k_find<<<dim3(8), dim3(1024), 0, stream>>>(p);
  k_compact<<<dim3(136), dim3(1024), 0, stream>>>(p);
  k_fill<<<dim3(10), dim3(256), 0, stream>>>(p);
  k_rank<<<dim3(80), dim3(256), 0, stream>>>(p);
  k_scatter<<<dim3(10), dim3(1024), 0, stream>>>(p);
  k_iou<<<dim3(250), dim3(256), 0, stream>>>(p);
  k_greedy<<<dim3(10), dim3(128), 0, stream>>>(p);
  k_post<<<dim3(10), dim3(256), 0, stream>>>(p);
  k_finalA<<<dim3(16), dim3(1024), 0, stream>>>(p);
  k_finalB<<<dim3(2), dim3(1024), 0, stream>>>(p);
}

// Round 6
// 552.679 us; speedup vs baseline: 1.9171x; 1.0974x over previous
//
#include <hip/hip_runtime.h>
#include <cmath>

// ---------------------------------------------------------------------------
// RPN head post-processing (mmdet GetBboxes-style), exact-semantics HIP port.
//
// Correctness: ordering-critical math fp64-exact (sigmoid, delta2bbox) or
// fp64-equivalent (IoU: fp32 filter + fp64 fallback band); top-k ordering on
// raw fp32 logit bits (monotone == fp64 sigmoid order; ties -> lower index).
//
// R1-R3 lesson: serial greedy scan cannot hold a register prefetch pipeline
// (spill -> scratch chain). R4: producer/consumer greedy (fast). R5: k_iou
// 4-row grouping (fast). R6: k_finalA was e-outer/j-inner => 3125 dependent
// LDS reads/thread on 16 blocks (108cy/iter, 141us). Now j-outer with 5
// register-cached e-keys per thread (k_rank pattern: 1 ds_read feeds 25
// VALU) and 64 blocks; k_finalB widened 2->10 blocks.
// ---------------------------------------------------------------------------

#define NPRE 2000
#define NPOST 1000

static __device__ __forceinline__ unsigned int flipf_dev(float f) {
  unsigned int u = __float_as_uint(f);
  return (u & 0x80000000u) ? ~u : (u | 0x80000000u);
}
static __device__ __forceinline__ float unflipf_dev(unsigned int k) {
  unsigned int u = (k & 0x80000000u) ? (k ^ 0x80000000u) : ~k;
  return __uint_as_float(u);
}
static __device__ __forceinline__ unsigned long long flip64_dev(double d) {
  unsigned long long u = (unsigned long long)__double_as_longlong(d);
  return (u & 0x8000000000000000ull) ? ~u : (u | 0x8000000000000000ull);
}

struct RPNParams {
  const float* cls[5];
  const float* bbox[5];
  const float* anc[5];
  unsigned int* hist;          // [10][65536]
  unsigned int* mainCount;     // [10]
  unsigned int* candCount;     // [10]
  unsigned int* Bstar;         // [10]
  unsigned long long* mainEK;  // [10][2048]  packed (key<<32)|~idx
  unsigned long long* candEK;  // [10][8192]
  unsigned long long* ekG;     // [10][2048]  assembled top-2000 (+pads)
  unsigned int* partialR;      // [10][8][2048] sliced ranks
  double* selBoxes;            // [10][2000][4]
  double* selScores;           // [10][2000]
  unsigned long long* mask;    // [10][2000][32]
  unsigned long long* keeps;   // [10][32]
  double* postScores;          // [10][1000]
  float* postBoxes;            // [10][1000][4]
  unsigned int* partial;       // [16][5000]
  float* out;                  // [2][1000][4]
};

__device__ __constant__ int c_NL[5]  = {201600, 50400, 12600, 3150, 819};
__device__ __constant__ int c_HW[5]  = {67200, 16800, 4200, 1050, 273};
__device__ __constant__ int c_BPT[8] = {50, 50, 13, 13, 4, 4, 1, 1};

static __device__ __forceinline__ void map_block(int bx, int& t, int& chunk) {
  int start = 0;
  t = 0;
  for (int k = 0; k < 8; k++) {
    if (bx < start + c_BPT[k]) { t = k; break; }
    start += c_BPT[k];
  }
  chunk = bx - start;
}

// --- 1. per-task 16-bit-bucket histogram of flipped logit keys --------------
__global__ void k_hist(RPNParams p) {
  int t, chunk;
  map_block(blockIdx.x, t, chunk);
  int l = t >> 1, b = t & 1;
  int N = c_NL[l], HW = c_HW[l];
  const float* cls = p.cls[l] + (size_t)b * 3 * HW;
  unsigned int* hist = p.hist + (size_t)t * 65536;
  int base = chunk * 4096 + threadIdx.x;
  for (int k = 0; k < 4; k++) {
    int n = base + k * 1024;
    if (n < N) {
      int a = n % 3, hw = n / 3;
      unsigned int key = flipf_dev(cls[a * HW + hw]);
      atomicAdd(&hist[key >> 16], 1u);
    }
  }
}

// --- 2. find threshold bucket B* per task -----------------------------------
__global__ void k_find(RPNParams p) {
  int t = blockIdx.x;  // 0..7
  unsigned int* hist = p.hist + (size_t)t * 65536;
  __shared__ unsigned int S[1024];
  __shared__ int gsel;
  __shared__ unsigned int baseAbove;
  int g = threadIdx.x;
  unsigned int s = 0;
  for (int j = 0; j < 64; j++) s += hist[g * 64 + j];
  S[g] = s;
  __syncthreads();
  for (int off = 1; off < 1024; off <<= 1) {
    unsigned int add = (g + off < 1024) ? S[g + off] : 0u;
    __syncthreads();
    S[g] += add;
    __syncthreads();
  }
  const unsigned int need = NPRE;
  if (S[g] >= need && (g == 1023 || S[g + 1] < need)) {
    gsel = g;
    baseAbove = (g == 1023) ? 0u : S[g + 1];
  }
  __syncthreads();
  if (threadIdx.x == 0) {
    int gg = gsel;
    unsigned int c = baseAbove;
    int bstar = gg * 64;
    for (int bb = gg * 64 + 63; bb >= gg * 64; bb--) {
      c += hist[bb];
      if (c >= need) { bstar = bb; break; }
    }
    p.Bstar[t] = (unsigned int)bstar;
  }
}

// --- 3. compaction: above-bucket -> main, == bucket -> cand -----------------
__global__ void k_compact(RPNParams p) {
  int t, chunk;
  map_block(blockIdx.x, t, chunk);
  int l = t >> 1, b = t & 1;
  int N = c_NL[l], HW = c_HW[l];
  const float* cls = p.cls[l] + (size_t)b * 3 * HW;
  unsigned int Bs = p.Bstar[t];
  int base = chunk * 4096 + threadIdx.x;
  for (int k = 0; k < 4; k++) {
    int n = base + k * 1024;
    if (n < N) {
      int a = n % 3, hw = n / 3;
      unsigned int key = flipf_dev(cls[a * HW + hw]);
      unsigned int hi = key >> 16;
      unsigned long long ek =
          ((unsigned long long)key << 32) | (unsigned int)(~(unsigned int)n);
      if (hi > Bs) {
        unsigned int pos = atomicAdd(&p.mainCount[t], 1u);
        if (pos < 2048u) p.mainEK[(size_t)t * 2048 + pos] = ek;
      } else if (hi == Bs) {
        unsigned int pos = atomicAdd(&p.candCount[t], 1u);
        if (pos < 8192u) p.candEK[(size_t)t * 8192 + pos] = ek;
      }
    }
  }
}

// --- 4a. fill ekG[t][2048]: exact top-2000 keys + pads ----------------------
__global__ void k_fill(RPNParams p) {
  int t = blockIdx.x;  // 0..9
  int l = t >> 1, b = t & 1;
  int N = c_NL[l], HW = c_HW[l];
  int tid = threadIdx.x;  // 256
  unsigned long long* ekG = p.ekG + (size_t)t * 2048;
  if (N >= NPRE) {
    unsigned int cGT = min(p.mainCount[t], 2000u);
    unsigned int nC = min(p.candCount[t], 8192u);
    unsigned int needIn = 2000u - cGT;
    for (unsigned int m = tid; m < cGT; m += 256)
      ekG[m] = p.mainEK[(size_t)t * 2048 + m];
    const unsigned long long* cek = p.candEK + (size_t)t * 8192;
    for (unsigned int e = tid; e < nC; e += 256) {
      unsigned long long ve = cek[e];
      unsigned int r = 0;
      for (unsigned int j = 0; j < nC; j++) r += (cek[j] > ve) ? 1u : 0u;
      if (r < needIn) ekG[cGT + r] = ve;
    }
    for (unsigned int r = 2000u + tid; r < 2048u; r += 256)
      ekG[r] = (unsigned long long)(unsigned int)(~r);
  } else {
    // level 4 (N=819): pad path -- key 0 pads below all finite logits
    const float* cls = p.cls[l] + (size_t)b * 3 * HW;
    for (int r = tid; r < 2048; r += 256) {
      if (r < N) {
        int a = r % 3, hw = r / 3;
        unsigned int key = flipf_dev(cls[a * HW + hw]);
        ekG[r] = ((unsigned long long)key << 32) |
                 (unsigned int)(~(unsigned int)r);
      } else {
        ekG[r] = (unsigned long long)(unsigned int)(~(unsigned int)r);
      }
    }
  }
}

// --- 4b. sliced counting-rank: 8 slices x 10 tasks --------------------------
__global__ void k_rank(RPNParams p) {
  int t = blockIdx.x >> 3;
  int s = blockIdx.x & 7;
  int tid = threadIdx.x;  // 256
  __shared__ unsigned long long sl[256];
  const unsigned long long* ekG = p.ekG + (size_t)t * 2048;
  sl[tid] = ekG[s * 256 + tid];
  __syncthreads();
  unsigned long long ve[8];
  unsigned int r[8];
#pragma unroll
  for (int k = 0; k < 8; k++) {
    ve[k] = ekG[k * 256 + tid];
    r[k] = 0;
  }
  for (int j = 0; j < 256; j++) {
    unsigned long long vj = sl[j];
#pragma unroll
    for (int k = 0; k < 8; k++) r[k] += (vj > ve[k]) ? 1u : 0u;
  }
  unsigned int* out = p.partialR + ((size_t)t * 8 + s) * 2048;
#pragma unroll
  for (int k = 0; k < 8; k++) out[k * 256 + tid] = r[k];
}

// --- 4c. scatter by total rank + fp64 decode --------------------------------
__global__ void k_scatter(RPNParams p) {
  int t = blockIdx.x;  // 0..9
  int l = t >> 1, b = t & 1;
  int HW = c_HW[l];
  int tid = threadIdx.x;  // 1024
  __shared__ unsigned long long srt[2048];
  const unsigned long long* ekG = p.ekG + (size_t)t * 2048;
  for (int e = tid; e < 2048; e += 1024) {
    unsigned int rk = 0;
#pragma unroll
    for (int s = 0; s < 8; s++)
      rk += p.partialR[((size_t)t * 8 + s) * 2048 + e];
    srt[rk] = ekG[e];
  }
  __syncthreads();

  const double RCLIP = fabs(log(16.0 / 1000.0));  // mmdet wh_ratio_clip
  const float* bbx = p.bbox[l] + (size_t)b * 12 * HW;
  const float* anc = p.anc[l];
  for (int r = tid; r < NPRE; r += 1024) {
    unsigned long long v = srt[r];
    unsigned int key = (unsigned int)(v >> 32);
    double* SB = p.selBoxes + ((size_t)t * NPRE + r) * 4;
    if (key == 0u) {  // pad: zero anchors/deltas -> zero box, score -1
      SB[0] = 0.0; SB[1] = 0.0; SB[2] = 0.0; SB[3] = 0.0;
      p.selScores[(size_t)t * NPRE + r] = -1.0;
    } else {
      unsigned int idx = ~(unsigned int)(v & 0xFFFFFFFFull);
      int a = (int)(idx % 3u);
      int hw = (int)(idx / 3u);
      double d0 = (double)bbx[(a * 4 + 0) * HW + hw];
      double d1 = (double)bbx[(a * 4 + 1) * HW + hw];
      double d2 = (double)bbx[(a * 4 + 2) * HW + hw];
      double d3 = (double)bbx[(a * 4 + 3) * HW + hw];
      double a0 = (double)anc[(size_t)idx * 4 + 0];
      double a1 = (double)anc[(size_t)idx * 4 + 1];
      double a2 = (double)anc[(size_t)idx * 4 + 2];
      double a3 = (double)anc[(size_t)idx * 4 + 3];
      double dw = fmin(fmax(d2, -RCLIP), RCLIP);
      double dh = fmin(fmax(d3, -RCLIP), RCLIP);
      double pw = a2 - a0, ph = a3 - a1;
      double px = (a0 + a2) * 0.5, py = (a1 + a3) * 0.5;
      double gw = pw * exp(dw), gh = ph * exp(dh);
      double gx = px + pw * d0, gy = py + ph * d1;
      double x1 = fmin(fmax(gx - 0.5 * gw, 0.0), 1344.0);
      double y1 = fmin(fmax(gy - 0.5 * gh, 0.0), 800.0);
      double x2 = fmin(fmax(gx + 0.5 * gw, 0.0), 1344.0);
      double y2 = fmin(fmax(gy + 0.5 * gh, 0.0), 800.0);
      SB[0] = x1; SB[1] = y1; SB[2] = x2; SB[3] = y2;
      float f = unflipf_dev(key);
      p.selScores[(size_t)t * NPRE + r] = 1.0 / (1.0 + exp(-(double)f));
    }
  }
}

// --- 5. IoU -> suppression bitmask. 4 rows share each column load. ----------
__global__ void k_iou(RPNParams p) {
  int bx = blockIdx.x;  // 250 blocks = 25 per task
  int t = bx / 25;
  int q = bx % 25;
  __shared__ float X1[2048], Y1[2048], X2[2048], Y2[2048], AR[2048];
  const double* SB = p.selBoxes + (size_t)t * NPRE * 4;
  for (int i = threadIdx.x; i < 2048; i += 256) {
    float x1 = 0.f, y1 = 0.f, x2 = 0.f, y2 = 0.f;
    if (i < NPRE) {
      x1 = (float)SB[i * 4 + 0]; y1 = (float)SB[i * 4 + 1];
      x2 = (float)SB[i * 4 + 2]; y2 = (float)SB[i * 4 + 3];
    }
    X1[i] = x1; Y1[i] = y1; X2[i] = x2; Y2[i] = y2;
    AR[i] = (x2 - x1) * (y2 - y1);
  }
  __syncthreads();
  int wave = threadIdx.x >> 6, lane = threadIdx.x & 63;
  for (int s = 0; s < 5; s++) {
    int g = q + 25 * (wave + 4 * s);  // [0,500), strided for balance
    int i0 = g * 4;
    float x1i[4], y1i[4], x2i[4], y2i[4], ai[4];
#pragma unroll
    for (int r = 0; r < 4; r++) {
      int i = i0 + r;
      x1i[r] = X1[i]; y1i[r] = Y1[i]; x2i[r] = X2[i]; y2i[r] = Y2[i];
      ai[r] = AR[i];
    }
    int c0 = i0 >> 6;
    for (int k = c0; k < 32; k++) {
      int j = k * 64 + lane;
      float xj1 = X1[j], yj1 = Y1[j], xj2 = X2[j], yj2 = Y2[j], arj = AR[j];
      bool jin = j < NPRE;
#pragma unroll
      for (int r = 0; r < 4; r++) {
        int i = i0 + r;
        bool valid = jin && (j > i);
        float lx = fmaxf(x1i[r], xj1), ly = fmaxf(y1i[r], yj1);
        float rx = fminf(x2i[r], xj2), ry = fminf(y2i[r], yj2);
        float w = fmaxf(rx - lx, 0.0f), h = fmaxf(ry - ly, 0.0f);
        float inter = w * h;
        float uni = fmaxf(ai[r] + arj - inter, 1e-6f);
        float diff = inter - 0.7f * uni;
        bool pred = (diff > 0.0f) && valid;
        if (valid && fabsf(diff) <= 4.0f + 1e-5f * uni) {
          // exact fp64 fallback (rare: only near the 0.7 boundary)
          double a0 = SB[i * 4 + 0], b0 = SB[i * 4 + 1];
          double a2 = SB[i * 4 + 2], b2 = SB[i * 4 + 3];
          double c0d = SB[j * 4 + 0], d0 = SB[j * 4 + 1];
          double c2 = SB[j * 4 + 2], d2 = SB[j * 4 + 3];
          double dai = (a2 - a0) * (b2 - b0);
          double daj = (c2 - c0d) * (d2 - d0);
          double lxd = fmax(a0, c0d), lyd = fmax(b0, d0);
          double rxd = fmin(a2, c2), ryd = fmin(b2, d2);
          double wd = fmax(rxd - lxd, 0.0), hd = fmax(ryd - lyd, 0.0);
          double interd = wd * hd;
          double unid = fmax(dai + daj - interd, 1e-6);
          pred = (interd / unid) > 0.7;
        }
        unsigned long long word = __ballot(pred);
        if (lane == 0) p.mask[((size_t)t * NPRE + i) * 32 + k] = word;
      }
    }
  }
}

// --- 6. greedy NMS: producer/consumer wave specialization, 1 block/task -----
#define RING 12
__global__ __launch_bounds__(128) void k_greedy(RPNParams p) {
  int t = blockIdx.x;
  int tid = threadIdx.x;
  __shared__ unsigned long long ring[RING * 512];  // 12 * 4 KB = 48 KB
  __shared__ int prog_s, cons_s;
  volatile int* prog = &prog_s;
  volatile int* cons = &cons_s;
  const unsigned long long* MK = p.mask + (size_t)t * NPRE * 32;
  if (tid == 0) { prog_s = 0; cons_s = 0; }
  __syncthreads();

  if (tid >= 64) {
    // ---------------- producer wave ----------------
    int lane = tid - 64;
    for (int g = 0; g < 125; g++) {
      while (g - *cons >= RING) __builtin_amdgcn_s_sleep(8);
      unsigned long long v[8];
#pragma unroll
      for (int k = 0; k < 8; k++)
        v[k] = MK[(size_t)g * 512 + k * 64 + lane];
      int slot = g % RING;
#pragma unroll
      for (int k = 0; k < 8; k++)
        ring[slot * 512 + k * 64 + lane] = v[k];
      __threadfence_block();  // data visible before publish
      if (lane == 0) *prog = g + 1;
    }
  } else {
    // ---------------- consumer wave ----------------
    int lane = tid;  // 0..63
    unsigned long long supp = 0ull, keep = 0ull;
    for (int g = 0; g < 125; g++) {
      while (*prog < g + 1) __builtin_amdgcn_s_sleep(2);
      int slot = g % RING;
      int c = g >> 2;  // owner chunk (16 rows per group, 4 groups per chunk)
      unsigned long long rv[16];
#pragma unroll
      for (int r = 0; r < 16; r++)
        rv[r] = ring[slot * 512 + r * 32 + (lane & 31)];
      unsigned int kg = 0;
      if (lane == c) {
        unsigned long long s = supp;
        int base = (g & 3) * 16;  // bit offset within the 64-bit chunk word
#pragma unroll
        for (int r = 0; r < 16; r++) {
          int b = base + r;
          if (!((s >> b) & 1ull)) {
            kg |= 1u << r;
            s |= rv[r];
          }
        }
        supp = s;
        keep |= (unsigned long long)kg << base;
      }
      kg = (unsigned int)__shfl((int)kg, c);
      if (lane != c) {
#pragma unroll
        for (int r = 0; r < 16; r++)
          supp |= ((kg >> r) & 1u) ? rv[r] : 0ull;
      }
      __threadfence_block();  // rv reads retired before freeing slot
      if (lane == 63) *cons = g + 1;
    }
    if (lane < 32) p.keeps[(size_t)t * 32 + lane] = keep;
  }
}

// --- 7. per-task re-rank: kept(+score) first (idx order), then -1 group -----
__global__ void k_post(RPNParams p) {
  int t = blockIdx.x;
  __shared__ unsigned long long kw[32], aw[32], bw[32];
  __shared__ unsigned int prefA[33], prefB[33];
  int tid = threadIdx.x;  // 256
  if (tid < 32) kw[tid] = p.keeps[(size_t)t * 32 + tid];
  __syncthreads();
  int wave = tid >> 6, lane = tid & 63;
  for (int ch = wave; ch < 32; ch += 4) {
    int i = ch * 64 + lane;
    bool inr = i < NPRE;
    bool kb = inr && ((kw[ch] >> lane) & 1ull);
    bool A = kb && (inr ? (p.selScores[(size_t)t * NPRE + i] > -0.5) : false);
    bool B = inr && !A;
    unsigned long long wa = __ballot(A);
    unsigned long long wb = __ballot(B);
    if (lane == 0) { aw[ch] = wa; bw[ch] = wb; }
  }
  __syncthreads();
  if (tid == 0) {
    unsigned int ca = 0, cb = 0;
    for (int w = 0; w < 32; w++) {
      prefA[w] = ca; ca += __popcll(aw[w]);
      prefB[w] = cb; cb += __popcll(bw[w]);
    }
    prefA[32] = ca; prefB[32] = cb;
  }
  __syncthreads();
  unsigned int KA = prefA[32];
  for (int i = tid; i < NPRE; i += 256) {
    int w = i >> 6, bpos = i & 63;
    unsigned long long below = (bpos == 0) ? 0ull : (~0ull >> (64 - bpos));
    bool kb = (kw[w] >> bpos) & 1ull;
    double s = p.selScores[(size_t)t * NPRE + i];
    bool A = kb && (s > -0.5);
    unsigned int slot;
    double outs;
    if (A) {
      slot = prefA[w] + (unsigned int)__popcll(aw[w] & below);
      outs = s;
    } else {
      slot = KA + prefB[w] + (unsigned int)__popcll(bw[w] & below);
      outs = -1.0;
    }
    if (slot < NPOST) {
      p.postScores[(size_t)t * NPOST + slot] = outs;
      const double* SB = p.selBoxes + ((size_t)t * NPRE + i) * 4;
      float* PB = p.postBoxes + ((size_t)t * NPOST + slot) * 4;
      PB[0] = (float)SB[0]; PB[1] = (float)SB[1];
      PB[2] = (float)SB[2]; PB[3] = (float)SB[3];
    }
  }
}

// --- 8a. final cross-level top-1000: sliced counting-rank (j-outer) ---------
// Grid: 2 images x 8 j-slices x 4 e-chunks = 64 blocks, 256 threads.
// Each thread register-caches 5 e-keys; one LDS read of kj[j] feeds 5
// independent rank compares (k_rank pattern -- was e-outer/j-inner with
// 3125 dependent LDS reads per thread on 16 blocks = 141us latency-bound).
__global__ void k_finalA(RPNParams p) {
  int bx = blockIdx.x;
  int b = bx >> 5;        // image 0..1
  int s = (bx >> 2) & 7;  // j-slice 0..7
  int ec = bx & 3;        // e-chunk 0..3
  int j0 = s * 625;
  __shared__ unsigned long long kj[625];
  int tid = threadIdx.x;  // 256
  for (int j = tid; j < 625; j += 256) {
    int e = j0 + j;
    int l = e / 1000, slot = e - l * 1000;
    int t = l * 2 + b;
    kj[j] = flip64_dev(p.postScores[(size_t)t * NPOST + slot]);
  }
  __syncthreads();
  int eidx[5];
  unsigned long long ke[5];
  unsigned int r[5];
#pragma unroll
  for (int k = 0; k < 5; k++) {
    int e = ec * 1280 + k * 256 + tid;
    eidx[k] = (e < 5000) ? e : -1;
    if (eidx[k] >= 0) {
      int l = e / 1000, slot = e - l * 1000;
      int t = l * 2 + b;
      ke[k] = flip64_dev(p.postScores[(size_t)t * NPOST + slot]);
    } else {
      ke[k] = 0ull;
    }
    r[k] = 0;
  }
  for (int j = 0; j < 625; j++) {
    unsigned long long vj = kj[j];
    int jg = j0 + j;
#pragma unroll
    for (int k = 0; k < 5; k++)
      r[k] += (vj > ke[k] || (vj == ke[k] && jg < eidx[k])) ? 1u : 0u;
  }
#pragma unroll
  for (int k = 0; k < 5; k++)
    if (eidx[k] >= 0)
      p.partial[((size_t)b * 8 + s) * 5000 + eidx[k]] = r[k];
}

// --- 8b. reduce ranks, gather output boxes ----------------------------------
__global__ void k_finalB(RPNParams p) {
  int b = blockIdx.x / 5;
  int ch = blockIdx.x % 5;
  int tid = threadIdx.x;  // 1024
  if (tid < 1000) {
    int e = ch * 1000 + tid;
    unsigned int r = 0;
#pragma unroll
    for (int s = 0; s < 8; s++) r += p.partial[((size_t)b * 8 + s) * 5000 + e];
    if (r < NPOST) {
      int l = e / 1000, slot = e - l * 1000;
      int t = l * 2 + b;
      const float* PB = p.postBoxes + ((size_t)t * NPOST + slot) * 4;
      float* O = p.out + ((size_t)b * NPOST + r) * 4;
      O[0] = PB[0]; O[1] = PB[1]; O[2] = PB[2]; O[3] = PB[3];
    }
  }
}

extern "C" void kernel_launch(void* const* d_in, const int* in_sizes, int n_in,
                              void* d_out, int out_size, void* d_ws,
                              size_t ws_size, hipStream_t stream) {
  RPNParams p;
  bool interleaved = (n_in >= 2) && (in_sizes[1] == 4 * in_sizes[0]);
  for (int l = 0; l < 5; l++) {
    if (interleaved) {
      p.cls[l]  = (const float*)d_in[3 * l + 0];
      p.bbox[l] = (const float*)d_in[3 * l + 1];
      p.anc[l]  = (const float*)d_in[3 * l + 2];
    } else {
      p.cls[l]  = (const float*)d_in[l];
      p.bbox[l] = (const float*)d_in[5 + l];
      p.anc[l]  = (const float*)d_in[10 + l];
    }
  }
  char* w = (char*)d_ws;
  size_t off = 0;
  auto alloc = [&](size_t bytes) {
    off = (off + 255) & ~(size_t)255;
    void* r = w + off;
    off += bytes;
    return r;
  };
  p.hist      = (unsigned int*)alloc((size_t)10 * 65536 * 4);
  p.mainCount = (unsigned int*)alloc(10 * 4);
  p.candCount = (unsigned int*)alloc(10 * 4);
  size_t zbytes = off;  // zeroed region: hist + atomic counters
  p.Bstar      = (unsigned int*)alloc(10 * 4);
  p.mainEK     = (unsigned long long*)alloc((size_t)10 * 2048 * 8);
  p.candEK     = (unsigned long long*)alloc((size_t)10 * 8192 * 8);
  p.ekG        = (unsigned long long*)alloc((size_t)10 * 2048 * 8);
  p.partialR   = (unsigned int*)alloc((size_t)10 * 8 * 2048 * 4);
  p.selBoxes   = (double*)alloc((size_t)10 * NPRE * 4 * 8);
  p.selScores  = (double*)alloc((size_t)10 * NPRE * 8);
  p.mask       = (unsigned long long*)alloc((size_t)10 * NPRE * 32 * 8);
  p.keeps      = (unsigned long long*)alloc((size_t)10 * 32 * 8);
  p.postScores = (double*)alloc((size_t)10 * NPOST * 8);
  p.postBoxes  = (float*)alloc((size_t)10 * NPOST * 4 * 4);
  p.partial    = (unsigned int*)alloc((size_t)16 * 5000 * 4);
  p.out = (float*)d_out;
  (void)ws_size; (void)out_size;

  hipMemsetAsync(d_ws, 0, zbytes, stream);
  k_hist<<<dim3(136), dim3(1024), 0, stream>>>(p);
  k_find<<<dim3(8), dim3(1024), 0, stream>>>(p);
  k_compact<<<dim3(136), dim3(1024), 0, stream>>>(p);
  k_fill<<<dim3(10), dim3(256), 0, stream>>>(p);
  k_rank<<<dim3(80), dim3(256), 0, stream>>>(p);
  k_scatter<<<dim3(10), dim3(1024), 0, stream>>>(p);
  k_iou<<<dim3(250), dim3(256), 0, stream>>>(p);
  k_greedy<<<dim3(10), dim3(128), 0, stream>>>(p);
  k_post<<<dim3(10), dim3(256), 0, stream>>>(p);
  k_finalA<<<dim3(64), dim3(256), 0, stream>>>(p);
  k_finalB<<<dim3(10), dim3(1024), 0, stream>>>(p);
}

// Round 7
// 548.441 us; speedup vs baseline: 1.9319x; 1.0077x over previous
//
#include <hip/hip_runtime.h>
#include <cmath>

// ---------------------------------------------------------------------------
// RPN head post-processing (mmdet GetBboxes-style), exact-semantics HIP port.
//
// Correctness: ordering-critical math fp64-exact (sigmoid, delta2bbox) or
// fp64-equivalent (IoU: fp32 filter + fp64 fallback band); top-k ordering on
// raw fp32 logit bits (monotone == fp64 sigmoid order; ties -> lower index).
//
// R1-R3 lesson: serial greedy scan cannot hold a register prefetch pipeline
// (spill -> scratch). R4: producer/consumer greedy via LDS ring. R6 PM:
// single producer wave was itself latency-serialized (1843 cy/group: one
// full HBM latency per group + s_sleep quantization). R7: SEVEN producer
// waves (groups striped mod 7, per-group ready flags, 14-slot ring) so 7
// HBM latencies overlap; consumer busy-polls (no sleep quantization).
// ---------------------------------------------------------------------------

#define NPRE 2000
#define NPOST 1000

static __device__ __forceinline__ unsigned int flipf_dev(float f) {
  unsigned int u = __float_as_uint(f);
  return (u & 0x80000000u) ? ~u : (u | 0x80000000u);
}
static __device__ __forceinline__ float unflipf_dev(unsigned int k) {
  unsigned int u = (k & 0x80000000u) ? (k ^ 0x80000000u) : ~k;
  return __uint_as_float(u);
}
static __device__ __forceinline__ unsigned long long flip64_dev(double d) {
  unsigned long long u = (unsigned long long)__double_as_longlong(d);
  return (u & 0x8000000000000000ull) ? ~u : (u | 0x8000000000000000ull);
}

struct RPNParams {
  const float* cls[5];
  const float* bbox[5];
  const float* anc[5];
  unsigned int* hist;          // [10][65536]
  unsigned int* mainCount;     // [10]
  unsigned int* candCount;     // [10]
  unsigned int* Bstar;         // [10]
  unsigned long long* mainEK;  // [10][2048]  packed (key<<32)|~idx
  unsigned long long* candEK;  // [10][8192]
  unsigned long long* ekG;     // [10][2048]  assembled top-2000 (+pads)
  unsigned int* partialR;      // [10][8][2048] sliced ranks
  double* selBoxes;            // [10][2000][4]
  double* selScores;           // [10][2000]
  unsigned long long* mask;    // [10][2000][32]
  unsigned long long* keeps;   // [10][32]
  double* postScores;          // [10][1000]
  float* postBoxes;            // [10][1000][4]
  unsigned int* partial;       // [16][5000]
  float* out;                  // [2][1000][4]
};

__device__ __constant__ int c_NL[5]  = {201600, 50400, 12600, 3150, 819};
__device__ __constant__ int c_HW[5]  = {67200, 16800, 4200, 1050, 273};
__device__ __constant__ int c_BPT[8] = {50, 50, 13, 13, 4, 4, 1, 1};

static __device__ __forceinline__ void map_block(int bx, int& t, int& chunk) {
  int start = 0;
  t = 0;
  for (int k = 0; k < 8; k++) {
    if (bx < start + c_BPT[k]) { t = k; break; }
    start += c_BPT[k];
  }
  chunk = bx - start;
}

// --- 1. per-task 16-bit-bucket histogram of flipped logit keys --------------
__global__ void k_hist(RPNParams p) {
  int t, chunk;
  map_block(blockIdx.x, t, chunk);
  int l = t >> 1, b = t & 1;
  int N = c_NL[l], HW = c_HW[l];
  const float* cls = p.cls[l] + (size_t)b * 3 * HW;
  unsigned int* hist = p.hist + (size_t)t * 65536;
  int base = chunk * 4096 + threadIdx.x;
  for (int k = 0; k < 4; k++) {
    int n = base + k * 1024;
    if (n < N) {
      int a = n % 3, hw = n / 3;
      unsigned int key = flipf_dev(cls[a * HW + hw]);
      atomicAdd(&hist[key >> 16], 1u);
    }
  }
}

// --- 2. find threshold bucket B* per task -----------------------------------
__global__ void k_find(RPNParams p) {
  int t = blockIdx.x;  // 0..7
  unsigned int* hist = p.hist + (size_t)t * 65536;
  __shared__ unsigned int S[1024];
  __shared__ int gsel;
  __shared__ unsigned int baseAbove;
  int g = threadIdx.x;
  unsigned int s = 0;
  for (int j = 0; j < 64; j++) s += hist[g * 64 + j];
  S[g] = s;
  __syncthreads();
  for (int off = 1; off < 1024; off <<= 1) {
    unsigned int add = (g + off < 1024) ? S[g + off] : 0u;
    __syncthreads();
    S[g] += add;
    __syncthreads();
  }
  const unsigned int need = NPRE;
  if (S[g] >= need && (g == 1023 || S[g + 1] < need)) {
    gsel = g;
    baseAbove = (g == 1023) ? 0u : S[g + 1];
  }
  __syncthreads();
  if (threadIdx.x == 0) {
    int gg = gsel;
    unsigned int c = baseAbove;
    int bstar = gg * 64;
    for (int bb = gg * 64 + 63; bb >= gg * 64; bb--) {
      c += hist[bb];
      if (c >= need) { bstar = bb; break; }
    }
    p.Bstar[t] = (unsigned int)bstar;
  }
}

// --- 3. compaction: above-bucket -> main, == bucket -> cand -----------------
__global__ void k_compact(RPNParams p) {
  int t, chunk;
  map_block(blockIdx.x, t, chunk);
  int l = t >> 1, b = t & 1;
  int N = c_NL[l], HW = c_HW[l];
  const float* cls = p.cls[l] + (size_t)b * 3 * HW;
  unsigned int Bs = p.Bstar[t];
  int base = chunk * 4096 + threadIdx.x;
  for (int k = 0; k < 4; k++) {
    int n = base + k * 1024;
    if (n < N) {
      int a = n % 3, hw = n / 3;
      unsigned int key = flipf_dev(cls[a * HW + hw]);
      unsigned int hi = key >> 16;
      unsigned long long ek =
          ((unsigned long long)key << 32) | (unsigned int)(~(unsigned int)n);
      if (hi > Bs) {
        unsigned int pos = atomicAdd(&p.mainCount[t], 1u);
        if (pos < 2048u) p.mainEK[(size_t)t * 2048 + pos] = ek;
      } else if (hi == Bs) {
        unsigned int pos = atomicAdd(&p.candCount[t], 1u);
        if (pos < 8192u) p.candEK[(size_t)t * 8192 + pos] = ek;
      }
    }
  }
}

// --- 4a. fill ekG[t][2048]: exact top-2000 keys + pads ----------------------
__global__ void k_fill(RPNParams p) {
  int t = blockIdx.x;  // 0..9
  int l = t >> 1, b = t & 1;
  int N = c_NL[l], HW = c_HW[l];
  int tid = threadIdx.x;  // 256
  unsigned long long* ekG = p.ekG + (size_t)t * 2048;
  if (N >= NPRE) {
    unsigned int cGT = min(p.mainCount[t], 2000u);
    unsigned int nC = min(p.candCount[t], 8192u);
    unsigned int needIn = 2000u - cGT;
    for (unsigned int m = tid; m < cGT; m += 256)
      ekG[m] = p.mainEK[(size_t)t * 2048 + m];
    const unsigned long long* cek = p.candEK + (size_t)t * 8192;
    for (unsigned int e = tid; e < nC; e += 256) {
      unsigned long long ve = cek[e];
      unsigned int r = 0;
      for (unsigned int j = 0; j < nC; j++) r += (cek[j] > ve) ? 1u : 0u;
      if (r < needIn) ekG[cGT + r] = ve;
    }
    for (unsigned int r = 2000u + tid; r < 2048u; r += 256)
      ekG[r] = (unsigned long long)(unsigned int)(~r);
  } else {
    // level 4 (N=819): pad path -- key 0 pads below all finite logits
    const float* cls = p.cls[l] + (size_t)b * 3 * HW;
    for (int r = tid; r < 2048; r += 256) {
      if (r < N) {
        int a = r % 3, hw = r / 3;
        unsigned int key = flipf_dev(cls[a * HW + hw]);
        ekG[r] = ((unsigned long long)key << 32) |
                 (unsigned int)(~(unsigned int)r);
      } else {
        ekG[r] = (unsigned long long)(unsigned int)(~(unsigned int)r);
      }
    }
  }
}

// --- 4b. sliced counting-rank: 8 slices x 10 tasks --------------------------
__global__ void k_rank(RPNParams p) {
  int t = blockIdx.x >> 3;
  int s = blockIdx.x & 7;
  int tid = threadIdx.x;  // 256
  __shared__ unsigned long long sl[256];
  const unsigned long long* ekG = p.ekG + (size_t)t * 2048;
  sl[tid] = ekG[s * 256 + tid];
  __syncthreads();
  unsigned long long ve[8];
  unsigned int r[8];
#pragma unroll
  for (int k = 0; k < 8; k++) {
    ve[k] = ekG[k * 256 + tid];
    r[k] = 0;
  }
  for (int j = 0; j < 256; j++) {
    unsigned long long vj = sl[j];
#pragma unroll
    for (int k = 0; k < 8; k++) r[k] += (vj > ve[k]) ? 1u : 0u;
  }
  unsigned int* out = p.partialR + ((size_t)t * 8 + s) * 2048;
#pragma unroll
  for (int k = 0; k < 8; k++) out[k * 256 + tid] = r[k];
}

// --- 4c. scatter by total rank + fp64 decode --------------------------------
__global__ void k_scatter(RPNParams p) {
  int t = blockIdx.x;  // 0..9
  int l = t >> 1, b = t & 1;
  int HW = c_HW[l];
  int tid = threadIdx.x;  // 1024
  __shared__ unsigned long long srt[2048];
  const unsigned long long* ekG = p.ekG + (size_t)t * 2048;
  for (int e = tid; e < 2048; e += 1024) {
    unsigned int rk = 0;
#pragma unroll
    for (int s = 0; s < 8; s++)
      rk += p.partialR[((size_t)t * 8 + s) * 2048 + e];
    srt[rk] = ekG[e];
  }
  __syncthreads();

  const double RCLIP = fabs(log(16.0 / 1000.0));  // mmdet wh_ratio_clip
  const float* bbx = p.bbox[l] + (size_t)b * 12 * HW;
  const float* anc = p.anc[l];
  for (int r = tid; r < NPRE; r += 1024) {
    unsigned long long v = srt[r];
    unsigned int key = (unsigned int)(v >> 32);
    double* SB = p.selBoxes + ((size_t)t * NPRE + r) * 4;
    if (key == 0u) {  // pad: zero anchors/deltas -> zero box, score -1
      SB[0] = 0.0; SB[1] = 0.0; SB[2] = 0.0; SB[3] = 0.0;
      p.selScores[(size_t)t * NPRE + r] = -1.0;
    } else {
      unsigned int idx = ~(unsigned int)(v & 0xFFFFFFFFull);
      int a = (int)(idx % 3u);
      int hw = (int)(idx / 3u);
      double d0 = (double)bbx[(a * 4 + 0) * HW + hw];
      double d1 = (double)bbx[(a * 4 + 1) * HW + hw];
      double d2 = (double)bbx[(a * 4 + 2) * HW + hw];
      double d3 = (double)bbx[(a * 4 + 3) * HW + hw];
      double a0 = (double)anc[(size_t)idx * 4 + 0];
      double a1 = (double)anc[(size_t)idx * 4 + 1];
      double a2 = (double)anc[(size_t)idx * 4 + 2];
      double a3 = (double)anc[(size_t)idx * 4 + 3];
      double dw = fmin(fmax(d2, -RCLIP), RCLIP);
      double dh = fmin(fmax(d3, -RCLIP), RCLIP);
      double pw = a2 - a0, ph = a3 - a1;
      double px = (a0 + a2) * 0.5, py = (a1 + a3) * 0.5;
      double gw = pw * exp(dw), gh = ph * exp(dh);
      double gx = px + pw * d0, gy = py + ph * d1;
      double x1 = fmin(fmax(gx - 0.5 * gw, 0.0), 1344.0);
      double y1 = fmin(fmax(gy - 0.5 * gh, 0.0), 800.0);
      double x2 = fmin(fmax(gx + 0.5 * gw, 0.0), 1344.0);
      double y2 = fmin(fmax(gy + 0.5 * gh, 0.0), 800.0);
      SB[0] = x1; SB[1] = y1; SB[2] = x2; SB[3] = y2;
      float f = unflipf_dev(key);
      p.selScores[(size_t)t * NPRE + r] = 1.0 / (1.0 + exp(-(double)f));
    }
  }
}

// --- 5. IoU -> suppression bitmask. 4 rows share each column load. ----------
__global__ void k_iou(RPNParams p) {
  int bx = blockIdx.x;  // 250 blocks = 25 per task
  int t = bx / 25;
  int q = bx % 25;
  __shared__ float X1[2048], Y1[2048], X2[2048], Y2[2048], AR[2048];
  const double* SB = p.selBoxes + (size_t)t * NPRE * 4;
  for (int i = threadIdx.x; i < 2048; i += 256) {
    float x1 = 0.f, y1 = 0.f, x2 = 0.f, y2 = 0.f;
    if (i < NPRE) {
      x1 = (float)SB[i * 4 + 0]; y1 = (float)SB[i * 4 + 1];
      x2 = (float)SB[i * 4 + 2]; y2 = (float)SB[i * 4 + 3];
    }
    X1[i] = x1; Y1[i] = y1; X2[i] = x2; Y2[i] = y2;
    AR[i] = (x2 - x1) * (y2 - y1);
  }
  __syncthreads();
  int wave = threadIdx.x >> 6, lane = threadIdx.x & 63;
  for (int s = 0; s < 5; s++) {
    int g = q + 25 * (wave + 4 * s);  // [0,500), strided for balance
    int i0 = g * 4;
    float x1i[4], y1i[4], x2i[4], y2i[4], ai[4];
#pragma unroll
    for (int r = 0; r < 4; r++) {
      int i = i0 + r;
      x1i[r] = X1[i]; y1i[r] = Y1[i]; x2i[r] = X2[i]; y2i[r] = Y2[i];
      ai[r] = AR[i];
    }
    int c0 = i0 >> 6;
    for (int k = c0; k < 32; k++) {
      int j = k * 64 + lane;
      float xj1 = X1[j], yj1 = Y1[j], xj2 = X2[j], yj2 = Y2[j], arj = AR[j];
      bool jin = j < NPRE;
#pragma unroll
      for (int r = 0; r < 4; r++) {
        int i = i0 + r;
        bool valid = jin && (j > i);
        float lx = fmaxf(x1i[r], xj1), ly = fmaxf(y1i[r], yj1);
        float rx = fminf(x2i[r], xj2), ry = fminf(y2i[r], yj2);
        float w = fmaxf(rx - lx, 0.0f), h = fmaxf(ry - ly, 0.0f);
        float inter = w * h;
        float uni = fmaxf(ai[r] + arj - inter, 1e-6f);
        float diff = inter - 0.7f * uni;
        bool pred = (diff > 0.0f) && valid;
        if (valid && fabsf(diff) <= 4.0f + 1e-5f * uni) {
          // exact fp64 fallback (rare: only near the 0.7 boundary)
          double a0 = SB[i * 4 + 0], b0 = SB[i * 4 + 1];
          double a2 = SB[i * 4 + 2], b2 = SB[i * 4 + 3];
          double c0d = SB[j * 4 + 0], d0 = SB[j * 4 + 1];
          double c2 = SB[j * 4 + 2], d2 = SB[j * 4 + 3];
          double dai = (a2 - a0) * (b2 - b0);
          double daj = (c2 - c0d) * (d2 - d0);
          double lxd = fmax(a0, c0d), lyd = fmax(b0, d0);
          double rxd = fmin(a2, c2), ryd = fmin(b2, d2);
          double wd = fmax(rxd - lxd, 0.0), hd = fmax(ryd - lyd, 0.0);
          double interd = wd * hd;
          double unid = fmax(dai + daj - interd, 1e-6);
          pred = (interd / unid) > 0.7;
        }
        unsigned long long word = __ballot(pred);
        if (lane == 0) p.mask[((size_t)t * NPRE + i) * 32 + k] = word;
      }
    }
  }
}

// --- 6. greedy NMS: 7 producer waves + 1 consumer wave, 1 block/task --------
// Producers (waves 1..7): wave w handles groups g == w-1 (mod 7); 7 HBM
// latencies in flight. Per-group ready[] flags (out-of-order completion);
// 14-slot LDS ring (56 KB). Consumer (wave 0): busy-polls ready[g] (no
// sleep quantization), reads 16 row-words from LDS, owner-lane closure +
// one shfl broadcast per 16-row group.
#define RING 14
__global__ __launch_bounds__(512) void k_greedy(RPNParams p) {
  int t = blockIdx.x;
  int tid = threadIdx.x;
  __shared__ unsigned long long ring[RING * 512];  // 56 KB
  __shared__ int ready[125];
  __shared__ int cons_s;
  volatile int* rdy = ready;
  volatile int* cons = &cons_s;
  const unsigned long long* MK = p.mask + (size_t)t * NPRE * 32;
  for (int i = tid; i < 125; i += 512) ready[i] = 0;
  if (tid == 0) cons_s = 0;
  __syncthreads();

  int wave = tid >> 6, lane = tid & 63;
  if (wave >= 1) {
    // ---------------- producer waves (7) ----------------
    for (int g = wave - 1; g < 125; g += 7) {
      while (g - *cons >= RING) __builtin_amdgcn_s_sleep(4);
      unsigned long long v[8];
#pragma unroll
      for (int k = 0; k < 8; k++)
        v[k] = MK[(size_t)g * 512 + k * 64 + lane];
      int slot = g % RING;
#pragma unroll
      for (int k = 0; k < 8; k++)
        ring[slot * 512 + k * 64 + lane] = v[k];
      __threadfence_block();  // data visible before publish
      if (lane == 0) rdy[g] = 1;
    }
  } else {
    // ---------------- consumer wave ----------------
    unsigned long long supp = 0ull, keep = 0ull;
    for (int g = 0; g < 125; g++) {
      while (rdy[g] == 0) { }  // busy-poll: no sleep quantization
      __threadfence_block();
      int slot = g % RING;
      int c = g >> 2;  // owner chunk (16 rows/group, 4 groups/chunk)
      unsigned long long rv[16];
#pragma unroll
      for (int r = 0; r < 16; r++)
        rv[r] = ring[slot * 512 + r * 32 + (lane & 31)];
      unsigned int kg = 0;
      if (lane == c) {
        unsigned long long s = supp;
        int base = (g & 3) * 16;  // bit offset within the 64-bit chunk word
#pragma unroll
        for (int r = 0; r < 16; r++) {
          int b = base + r;
          if (!((s >> b) & 1ull)) {
            kg |= 1u << r;
            s |= rv[r];
          }
        }
        supp = s;
        keep |= (unsigned long long)kg << base;
      }
      kg = (unsigned int)__shfl((int)kg, c);
      if (lane != c) {
#pragma unroll
        for (int r = 0; r < 16; r++)
          supp |= ((kg >> r) & 1u) ? rv[r] : 0ull;
      }
      __threadfence_block();  // rv reads retired before freeing slot
      if (lane == 63) *cons = g + 1;
    }
    if (lane < 32) p.keeps[(size_t)t * 32 + lane] = keep;
  }
}

// --- 7. per-task re-rank: kept(+score) first (idx order), then -1 group -----
__global__ void k_post(RPNParams p) {
  int t = blockIdx.x;
  __shared__ unsigned long long kw[32], aw[32], bw[32];
  __shared__ unsigned int prefA[33], prefB[33];
  int tid = threadIdx.x;  // 256
  if (tid < 32) kw[tid] = p.keeps[(size_t)t * 32 + tid];
  __syncthreads();
  int wave = tid >> 6, lane = tid & 63;
  for (int ch = wave; ch < 32; ch += 4) {
    int i = ch * 64 + lane;
    bool inr = i < NPRE;
    bool kb = inr && ((kw[ch] >> lane) & 1ull);
    bool A = kb && (inr ? (p.selScores[(size_t)t * NPRE + i] > -0.5) : false);
    bool B = inr && !A;
    unsigned long long wa = __ballot(A);
    unsigned long long wb = __ballot(B);
    if (lane == 0) { aw[ch] = wa; bw[ch] = wb; }
  }
  __syncthreads();
  if (tid == 0) {
    unsigned int ca = 0, cb = 0;
    for (int w = 0; w < 32; w++) {
      prefA[w] = ca; ca += __popcll(aw[w]);
      prefB[w] = cb; cb += __popcll(bw[w]);
    }
    prefA[32] = ca; prefB[32] = cb;
  }
  __syncthreads();
  unsigned int KA = prefA[32];
  for (int i = tid; i < NPRE; i += 256) {
    int w = i >> 6, bpos = i & 63;
    unsigned long long below = (bpos == 0) ? 0ull : (~0ull >> (64 - bpos));
    bool kb = (kw[w] >> bpos) & 1ull;
    double s = p.selScores[(size_t)t * NPRE + i];
    bool A = kb && (s > -0.5);
    unsigned int slot;
    double outs;
    if (A) {
      slot = prefA[w] + (unsigned int)__popcll(aw[w] & below);
      outs = s;
    } else {
      slot = KA + prefB[w] + (unsigned int)__popcll(bw[w] & below);
      outs = -1.0;
    }
    if (slot < NPOST) {
      p.postScores[(size_t)t * NPOST + slot] = outs;
      const double* SB = p.selBoxes + ((size_t)t * NPRE + i) * 4;
      float* PB = p.postBoxes + ((size_t)t * NPOST + slot) * 4;
      PB[0] = (float)SB[0]; PB[1] = (float)SB[1];
      PB[2] = (float)SB[2]; PB[3] = (float)SB[3];
    }
  }
}

// --- 8a. final cross-level top-1000: sliced counting-rank (j-outer) ---------
__global__ void k_finalA(RPNParams p) {
  int bx = blockIdx.x;
  int b = bx >> 5;        // image 0..1
  int s = (bx >> 2) & 7;  // j-slice 0..7
  int ec = bx & 3;        // e-chunk 0..3
  int j0 = s * 625;
  __shared__ unsigned long long kj[625];
  int tid = threadIdx.x;  // 256
  for (int j = tid; j < 625; j += 256) {
    int e = j0 + j;
    int l = e / 1000, slot = e - l * 1000;
    int t = l * 2 + b;
    kj[j] = flip64_dev(p.postScores[(size_t)t * NPOST + slot]);
  }
  __syncthreads();
  int eidx[5];
  unsigned long long ke[5];
  unsigned int r[5];
#pragma unroll
  for (int k = 0; k < 5; k++) {
    int e = ec * 1280 + k * 256 + tid;
    eidx[k] = (e < 5000) ? e : -1;
    if (eidx[k] >= 0) {
      int l = e / 1000, slot = e - l * 1000;
      int t = l * 2 + b;
      ke[k] = flip64_dev(p.postScores[(size_t)t * NPOST + slot]);
    } else {
      ke[k] = 0ull;
    }
    r[k] = 0;
  }
  for (int j = 0; j < 625; j++) {
    unsigned long long vj = kj[j];
    int jg = j0 + j;
#pragma unroll
    for (int k = 0; k < 5; k++)
      r[k] += (vj > ke[k] || (vj == ke[k] && jg < eidx[k])) ? 1u : 0u;
  }
#pragma unroll
  for (int k = 0; k < 5; k++)
    if (eidx[k] >= 0)
      p.partial[((size_t)b * 8 + s) * 5000 + eidx[k]] = r[k];
}

// --- 8b. reduce ranks, gather output boxes ----------------------------------
__global__ void k_finalB(RPNParams p) {
  int b = blockIdx.x / 5;
  int ch = blockIdx.x % 5;
  int tid = threadIdx.x;  // 1024
  if (tid < 1000) {
    int e = ch * 1000 + tid;
    unsigned int r = 0;
#pragma unroll
    for (int s = 0; s < 8; s++) r += p.partial[((size_t)b * 8 + s) * 5000 + e];
    if (r < NPOST) {
      int l = e / 1000, slot = e - l * 1000;
      int t = l * 2 + b;
      const float* PB = p.postBoxes + ((size_t)t * NPOST + slot) * 4;
      float* O = p.out + ((size_t)b * NPOST + r) * 4;
      O[0] = PB[0]; O[1] = PB[1]; O[2] = PB[2]; O[3] = PB[3];
    }
  }
}

extern "C" void kernel_launch(void* const* d_in, const int* in_sizes, int n_in,
                              void* d_out, int out_size, void* d_ws,
                              size_t ws_size, hipStream_t stream) {
  RPNParams p;
  bool interleaved = (n_in >= 2) && (in_sizes[1] == 4 * in_sizes[0]);
  for (int l = 0; l < 5; l++) {
    if (interleaved) {
      p.cls[l]  = (const float*)d_in[3 * l + 0];
      p.bbox[l] = (const float*)d_in[3 * l + 1];
      p.anc[l]  = (const float*)d_in[3 * l + 2];
    } else {
      p.cls[l]  = (const float*)d_in[l];
      p.bbox[l] = (const float*)d_in[5 + l];
      p.anc[l]  = (const float*)d_in[10 + l];
    }
  }
  char* w = (char*)d_ws;
  size_t off = 0;
  auto alloc = [&](size_t bytes) {
    off = (off + 255) & ~(size_t)255;
    void* r = w + off;
    off += bytes;
    return r;
  };
  p.hist      = (unsigned int*)alloc((size_t)10 * 65536 * 4);
  p.mainCount = (unsigned int*)alloc(10 * 4);
  p.candCount = (unsigned int*)alloc(10 * 4);
  size_t zbytes = off;  // zeroed region: hist + atomic counters
  p.Bstar      = (unsigned int*)alloc(10 * 4);
  p.mainEK     = (unsigned long long*)alloc((size_t)10 * 2048 * 8);
  p.candEK     = (unsigned long long*)alloc((size_t)10 * 8192 * 8);
  p.ekG        = (unsigned long long*)alloc((size_t)10 * 2048 * 8);
  p.partialR   = (unsigned int*)alloc((size_t)10 * 8 * 2048 * 4);
  p.selBoxes   = (double*)alloc((size_t)10 * NPRE * 4 * 8);
  p.selScores  = (double*)alloc((size_t)10 * NPRE * 8);
  p.mask       = (unsigned long long*)alloc((size_t)10 * NPRE * 32 * 8);
  p.keeps      = (unsigned long long*)alloc((size_t)10 * 32 * 8);
  p.postScores = (double*)alloc((size_t)10 * NPOST * 8);
  p.postBoxes  = (float*)alloc((size_t)10 * NPOST * 4 * 4);
  p.partial    = (unsigned int*)alloc((size_t)16 * 5000 * 4);
  p.out = (float*)d_out;
  (void)ws_size; (void)out_size;

  hipMemsetAsync(d_ws, 0, zbytes, stream);
  k_hist<<<dim3(136), dim3(1024), 0, stream>>>(p);
  k_find<<<dim3(8), dim3(1024), 0, stream>>>(p);
  k_compact<<<dim3(136), dim3(1024), 0, stream>>>(p);
  k_fill<<<dim3(10), dim3(256), 0, stream>>>(p);
  k_rank<<<dim3(80), dim3(256), 0, stream>>>(p);
  k_scatter<<<dim3(10), dim3(1024), 0, stream>>>(p);
  k_iou<<<dim3(250), dim3(256), 0, stream>>>(p);
  k_greedy<<<dim3(10), dim3(512), 0, stream>>>(p);
  k_post<<<dim3(10), dim3(256), 0, stream>>>(p);
  k_finalA<<<dim3(64), dim3(256), 0, stream>>>(p);
  k_finalB<<<dim3(10), dim3(1024), 0, stream>>>(p);
}

// Round 8
// 544.695 us; speedup vs baseline: 1.9452x; 1.0069x over previous
//
#include <hip/hip_runtime.h>
#include <cmath>

// ---------------------------------------------------------------------------
// RPN head post-processing (mmdet GetBboxes-style), exact-semantics HIP port.
//
// Correctness: ordering-critical math fp64-exact (sigmoid, delta2bbox) or
// fp64-equivalent (IoU: fp32 filter + fp64 fallback band); top-k ordering on
// raw fp32 logit bits (monotone == fp64 sigmoid order; ties -> lower index).
//
// R7 PM: k_iou at 92us was 1 wave/SIMD (occ 6%) -- exposed LDS latency +
// 4x exec-toggle per k-iter. R8: 1024-thread blocks (4 waves/SIMD),
// software-pipelined column prefetch, single __any branch for the fp64
// fallback; k_post fused into k_greedy (keeps stay on-chip); hist/compact
// at 2048 elems/block (266 blocks) for 2x CU coverage.
// ---------------------------------------------------------------------------

#define NPRE 2000
#define NPOST 1000

static __device__ __forceinline__ unsigned int flipf_dev(float f) {
  unsigned int u = __float_as_uint(f);
  return (u & 0x80000000u) ? ~u : (u | 0x80000000u);
}
static __device__ __forceinline__ float unflipf_dev(unsigned int k) {
  unsigned int u = (k & 0x80000000u) ? (k ^ 0x80000000u) : ~k;
  return __uint_as_float(u);
}
static __device__ __forceinline__ unsigned long long flip64_dev(double d) {
  unsigned long long u = (unsigned long long)__double_as_longlong(d);
  return (u & 0x8000000000000000ull) ? ~u : (u | 0x8000000000000000ull);
}

struct RPNParams {
  const float* cls[5];
  const float* bbox[5];
  const float* anc[5];
  unsigned int* hist;          // [10][65536]
  unsigned int* mainCount;     // [10]
  unsigned int* candCount;     // [10]
  unsigned int* Bstar;         // [10]
  unsigned long long* mainEK;  // [10][2048]  packed (key<<32)|~idx
  unsigned long long* candEK;  // [10][8192]
  unsigned long long* ekG;     // [10][2048]  assembled top-2000 (+pads)
  unsigned int* partialR;      // [10][8][2048] sliced ranks
  double* selBoxes;            // [10][2000][4]
  double* selScores;           // [10][2000]
  unsigned long long* mask;    // [10][2000][32]
  unsigned long long* keeps;   // [10][32] (unused since R8 fusion)
  double* postScores;          // [10][1000]
  float* postBoxes;            // [10][1000][4]
  unsigned int* partial;       // [16][5000]
  float* out;                  // [2][1000][4]
};

__device__ __constant__ int c_NL[5]  = {201600, 50400, 12600, 3150, 819};
__device__ __constant__ int c_HW[5]  = {67200, 16800, 4200, 1050, 273};
// blocks-per-task at 2048 elements/block (levels 0..3 x 2 images)
__device__ __constant__ int c_BPT[8] = {99, 99, 25, 25, 7, 7, 2, 2};

static __device__ __forceinline__ void map_block(int bx, int& t, int& chunk) {
  int start = 0;
  t = 0;
  for (int k = 0; k < 8; k++) {
    if (bx < start + c_BPT[k]) { t = k; break; }
    start += c_BPT[k];
  }
  chunk = bx - start;
}

// --- 1. per-task 16-bit-bucket histogram of flipped logit keys --------------
__global__ void k_hist(RPNParams p) {
  int t, chunk;
  map_block(blockIdx.x, t, chunk);
  int l = t >> 1, b = t & 1;
  int N = c_NL[l], HW = c_HW[l];
  const float* cls = p.cls[l] + (size_t)b * 3 * HW;
  unsigned int* hist = p.hist + (size_t)t * 65536;
  int base = chunk * 2048 + threadIdx.x;
  for (int k = 0; k < 2; k++) {
    int n = base + k * 1024;
    if (n < N) {
      int a = n % 3, hw = n / 3;
      unsigned int key = flipf_dev(cls[a * HW + hw]);
      atomicAdd(&hist[key >> 16], 1u);
    }
  }
}

// --- 2. find threshold bucket B* per task -----------------------------------
__global__ void k_find(RPNParams p) {
  int t = blockIdx.x;  // 0..7
  unsigned int* hist = p.hist + (size_t)t * 65536;
  __shared__ unsigned int S[1024];
  __shared__ int gsel;
  __shared__ unsigned int baseAbove;
  int g = threadIdx.x;
  unsigned int s = 0;
  for (int j = 0; j < 64; j++) s += hist[g * 64 + j];
  S[g] = s;
  __syncthreads();
  for (int off = 1; off < 1024; off <<= 1) {
    unsigned int add = (g + off < 1024) ? S[g + off] : 0u;
    __syncthreads();
    S[g] += add;
    __syncthreads();
  }
  const unsigned int need = NPRE;
  if (S[g] >= need && (g == 1023 || S[g + 1] < need)) {
    gsel = g;
    baseAbove = (g == 1023) ? 0u : S[g + 1];
  }
  __syncthreads();
  if (threadIdx.x == 0) {
    int gg = gsel;
    unsigned int c = baseAbove;
    int bstar = gg * 64;
    for (int bb = gg * 64 + 63; bb >= gg * 64; bb--) {
      c += hist[bb];
      if (c >= need) { bstar = bb; break; }
    }
    p.Bstar[t] = (unsigned int)bstar;
  }
}

// --- 3. compaction: above-bucket -> main, == bucket -> cand -----------------
__global__ void k_compact(RPNParams p) {
  int t, chunk;
  map_block(blockIdx.x, t, chunk);
  int l = t >> 1, b = t & 1;
  int N = c_NL[l], HW = c_HW[l];
  const float* cls = p.cls[l] + (size_t)b * 3 * HW;
  unsigned int Bs = p.Bstar[t];
  int base = chunk * 2048 + threadIdx.x;
  for (int k = 0; k < 2; k++) {
    int n = base + k * 1024;
    if (n < N) {
      int a = n % 3, hw = n / 3;
      unsigned int key = flipf_dev(cls[a * HW + hw]);
      unsigned int hi = key >> 16;
      unsigned long long ek =
          ((unsigned long long)key << 32) | (unsigned int)(~(unsigned int)n);
      if (hi > Bs) {
        unsigned int pos = atomicAdd(&p.mainCount[t], 1u);
        if (pos < 2048u) p.mainEK[(size_t)t * 2048 + pos] = ek;
      } else if (hi == Bs) {
        unsigned int pos = atomicAdd(&p.candCount[t], 1u);
        if (pos < 8192u) p.candEK[(size_t)t * 8192 + pos] = ek;
      }
    }
  }
}

// --- 4a. fill ekG[t][2048]: exact top-2000 keys + pads ----------------------
__global__ void k_fill(RPNParams p) {
  int t = blockIdx.x;  // 0..9
  int l = t >> 1, b = t & 1;
  int N = c_NL[l], HW = c_HW[l];
  int tid = threadIdx.x;  // 256
  unsigned long long* ekG = p.ekG + (size_t)t * 2048;
  if (N >= NPRE) {
    unsigned int cGT = min(p.mainCount[t], 2000u);
    unsigned int nC = min(p.candCount[t], 8192u);
    unsigned int needIn = 2000u - cGT;
    for (unsigned int m = tid; m < cGT; m += 256)
      ekG[m] = p.mainEK[(size_t)t * 2048 + m];
    const unsigned long long* cek = p.candEK + (size_t)t * 8192;
    for (unsigned int e = tid; e < nC; e += 256) {
      unsigned long long ve = cek[e];
      unsigned int r = 0;
      for (unsigned int j = 0; j < nC; j++) r += (cek[j] > ve) ? 1u : 0u;
      if (r < needIn) ekG[cGT + r] = ve;
    }
    for (unsigned int r = 2000u + tid; r < 2048u; r += 256)
      ekG[r] = (unsigned long long)(unsigned int)(~r);
  } else {
    // level 4 (N=819): pad path -- key 0 pads below all finite logits
    const float* cls = p.cls[l] + (size_t)b * 3 * HW;
    for (int r = tid; r < 2048; r += 256) {
      if (r < N) {
        int a = r % 3, hw = r / 3;
        unsigned int key = flipf_dev(cls[a * HW + hw]);
        ekG[r] = ((unsigned long long)key << 32) |
                 (unsigned int)(~(unsigned int)r);
      } else {
        ekG[r] = (unsigned long long)(unsigned int)(~(unsigned int)r);
      }
    }
  }
}

// --- 4b. sliced counting-rank: 8 slices x 10 tasks --------------------------
__global__ void k_rank(RPNParams p) {
  int t = blockIdx.x >> 3;
  int s = blockIdx.x & 7;
  int tid = threadIdx.x;  // 256
  __shared__ unsigned long long sl[256];
  const unsigned long long* ekG = p.ekG + (size_t)t * 2048;
  sl[tid] = ekG[s * 256 + tid];
  __syncthreads();
  unsigned long long ve[8];
  unsigned int r[8];
#pragma unroll
  for (int k = 0; k < 8; k++) {
    ve[k] = ekG[k * 256 + tid];
    r[k] = 0;
  }
  for (int j = 0; j < 256; j++) {
    unsigned long long vj = sl[j];
#pragma unroll
    for (int k = 0; k < 8; k++) r[k] += (vj > ve[k]) ? 1u : 0u;
  }
  unsigned int* out = p.partialR + ((size_t)t * 8 + s) * 2048;
#pragma unroll
  for (int k = 0; k < 8; k++) out[k * 256 + tid] = r[k];
}

// --- 4c. scatter by total rank + fp64 decode --------------------------------
__global__ void k_scatter(RPNParams p) {
  int t = blockIdx.x;  // 0..9
  int l = t >> 1, b = t & 1;
  int HW = c_HW[l];
  int tid = threadIdx.x;  // 1024
  __shared__ unsigned long long srt[2048];
  const unsigned long long* ekG = p.ekG + (size_t)t * 2048;
  for (int e = tid; e < 2048; e += 1024) {
    unsigned int rk = 0;
#pragma unroll
    for (int s = 0; s < 8; s++)
      rk += p.partialR[((size_t)t * 8 + s) * 2048 + e];
    srt[rk] = ekG[e];
  }
  __syncthreads();

  const double RCLIP = fabs(log(16.0 / 1000.0));  // mmdet wh_ratio_clip
  const float* bbx = p.bbox[l] + (size_t)b * 12 * HW;
  const float* anc = p.anc[l];
  for (int r = tid; r < NPRE; r += 1024) {
    unsigned long long v = srt[r];
    unsigned int key = (unsigned int)(v >> 32);
    double* SB = p.selBoxes + ((size_t)t * NPRE + r) * 4;
    if (key == 0u) {  // pad: zero anchors/deltas -> zero box, score -1
      SB[0] = 0.0; SB[1] = 0.0; SB[2] = 0.0; SB[3] = 0.0;
      p.selScores[(size_t)t * NPRE + r] = -1.0;
    } else {
      unsigned int idx = ~(unsigned int)(v & 0xFFFFFFFFull);
      int a = (int)(idx % 3u);
      int hw = (int)(idx / 3u);
      double d0 = (double)bbx[(a * 4 + 0) * HW + hw];
      double d1 = (double)bbx[(a * 4 + 1) * HW + hw];
      double d2 = (double)bbx[(a * 4 + 2) * HW + hw];
      double d3 = (double)bbx[(a * 4 + 3) * HW + hw];
      double a0 = (double)anc[(size_t)idx * 4 + 0];
      double a1 = (double)anc[(size_t)idx * 4 + 1];
      double a2 = (double)anc[(size_t)idx * 4 + 2];
      double a3 = (double)anc[(size_t)idx * 4 + 3];
      double dw = fmin(fmax(d2, -RCLIP), RCLIP);
      double dh = fmin(fmax(d3, -RCLIP), RCLIP);
      double pw = a2 - a0, ph = a3 - a1;
      double px = (a0 + a2) * 0.5, py = (a1 + a3) * 0.5;
      double gw = pw * exp(dw), gh = ph * exp(dh);
      double gx = px + pw * d0, gy = py + ph * d1;
      double x1 = fmin(fmax(gx - 0.5 * gw, 0.0), 1344.0);
      double y1 = fmin(fmax(gy - 0.5 * gh, 0.0), 800.0);
      double x2 = fmin(fmax(gx + 0.5 * gw, 0.0), 1344.0);
      double y2 = fmin(fmax(gy + 0.5 * gh, 0.0), 800.0);
      SB[0] = x1; SB[1] = y1; SB[2] = x2; SB[3] = y2;
      float f = unflipf_dev(key);
      p.selScores[(size_t)t * NPRE + r] = 1.0 / (1.0 + exp(-(double)f));
    }
  }
}

// --- 5. IoU -> suppression bitmask. 16 waves/block, pipelined columns. ------
// 100 blocks (10/task), 1024 threads: 4 waves/SIMD hide LDS latency.
// Per k-iter: prefetch k+1's 5 column floats while computing 4 rows' IoU;
// fp64 fallback merged into one __any branch (band is conservative:
// fp32 error << band => predicate identical to fp64 reference).
__global__ __launch_bounds__(1024) void k_iou(RPNParams p) {
  int bx = blockIdx.x;
  int t = bx / 10;
  int q = bx % 10;
  __shared__ float X1[2048], Y1[2048], X2[2048], Y2[2048], AR[2048];
  const double* SB = p.selBoxes + (size_t)t * NPRE * 4;
  for (int i = threadIdx.x; i < 2048; i += 1024) {
    float x1 = 0.f, y1 = 0.f, x2 = 0.f, y2 = 0.f;
    if (i < NPRE) {
      x1 = (float)SB[i * 4 + 0]; y1 = (float)SB[i * 4 + 1];
      x2 = (float)SB[i * 4 + 2]; y2 = (float)SB[i * 4 + 3];
    }
    X1[i] = x1; Y1[i] = y1; X2[i] = x2; Y2[i] = y2;
    AR[i] = (x2 - x1) * (y2 - y1);
  }
  __syncthreads();
  int wave = threadIdx.x >> 6, lane = threadIdx.x & 63;
  for (int s = 0; s < 4; s++) {
    int g = q + 10 * (wave + 16 * s);  // [0,500) strided for balance
    if (g >= 500) break;
    int i0 = g * 4;
    float x1i[4], y1i[4], x2i[4], y2i[4], ai[4];
#pragma unroll
    for (int r = 0; r < 4; r++) {
      int i = i0 + r;
      x1i[r] = X1[i]; y1i[r] = Y1[i]; x2i[r] = X2[i]; y2i[r] = Y2[i];
      ai[r] = AR[i];
    }
    int c0 = i0 >> 6;
    int j0 = c0 * 64 + lane;
    float cx1 = X1[j0], cy1 = Y1[j0], cx2 = X2[j0], cy2 = Y2[j0],
          car = AR[j0];
    for (int k = c0; k < 32; k++) {
      float nx1 = 0.f, ny1 = 0.f, nx2 = 0.f, ny2 = 0.f, nar = 0.f;
      if (k + 1 < 32) {  // prefetch next column word
        int jn = (k + 1) * 64 + lane;
        nx1 = X1[jn]; ny1 = Y1[jn]; nx2 = X2[jn]; ny2 = Y2[jn];
        nar = AR[jn];
      }
      int j = k * 64 + lane;
      bool jin = j < NPRE;
      bool pred[4], need[4];
      bool needAny = false;
#pragma unroll
      for (int r = 0; r < 4; r++) {
        int i = i0 + r;
        bool valid = jin && (j > i);
        float lx = fmaxf(x1i[r], cx1), ly = fmaxf(y1i[r], cy1);
        float rx = fminf(x2i[r], cx2), ry = fminf(y2i[r], cy2);
        float w = fmaxf(rx - lx, 0.0f), h = fmaxf(ry - ly, 0.0f);
        float inter = w * h;
        float uni = fmaxf(ai[r] + car - inter, 1e-6f);
        float diff = inter - 0.7f * uni;
        pred[r] = valid && (diff > 0.0f);
        need[r] = valid && (fabsf(diff) <= 4.0f + 1e-5f * uni);
        needAny |= need[r];
      }
      if (__any(needAny)) {  // rare: exact fp64 near the 0.7 boundary
#pragma unroll
        for (int r = 0; r < 4; r++) {
          if (need[r]) {
            int i = i0 + r;
            double a0 = SB[i * 4 + 0], b0 = SB[i * 4 + 1];
            double a2 = SB[i * 4 + 2], b2 = SB[i * 4 + 3];
            double c0d = SB[j * 4 + 0], d0 = SB[j * 4 + 1];
            double c2 = SB[j * 4 + 2], d2 = SB[j * 4 + 3];
            double dai = (a2 - a0) * (b2 - b0);
            double daj = (c2 - c0d) * (d2 - d0);
            double lxd = fmax(a0, c0d), lyd = fmax(b0, d0);
            double rxd = fmin(a2, c2), ryd = fmin(b2, d2);
            double wd = fmax(rxd - lxd, 0.0), hd = fmax(ryd - lyd, 0.0);
            double interd = wd * hd;
            double unid = fmax(dai + daj - interd, 1e-6);
            pred[r] = (interd / unid) > 0.7;
          }
        }
      }
#pragma unroll
      for (int r = 0; r < 4; r++) {
        unsigned long long word = __ballot(pred[r]);
        if (lane == 0) p.mask[((size_t)t * NPRE + i0 + r) * 32 + k] = word;
      }
      cx1 = nx1; cy1 = ny1; cx2 = nx2; cy2 = ny2; car = nar;
    }
  }
}

// --- 6. greedy NMS (7 producers + 1 consumer) FUSED with re-rank ------------
// Producers (waves 1..7): groups striped mod 7, per-group ready flags,
// 14-slot LDS ring. Consumer (wave 0): distributed-bitmask closure.
// After the scan, all 8 waves run the k_post re-rank (keeps stay in LDS).
#define RING 14
__global__ __launch_bounds__(512) void k_greedy(RPNParams p) {
  int t = blockIdx.x;
  int tid = threadIdx.x;
  __shared__ unsigned long long ring[RING * 512];  // 56 KB
  __shared__ int ready[125];
  __shared__ int cons_s;
  __shared__ unsigned long long kw[32], aw[32], bw[32];
  __shared__ unsigned int prefA[33], prefB[33];
  volatile int* rdy = ready;
  volatile int* cons = &cons_s;
  const unsigned long long* MK = p.mask + (size_t)t * NPRE * 32;
  for (int i = tid; i < 125; i += 512) ready[i] = 0;
  if (tid == 0) cons_s = 0;
  __syncthreads();

  int wave = tid >> 6, lane = tid & 63;
  if (wave >= 1) {
    // ---------------- producer waves (7) ----------------
    for (int g = wave - 1; g < 125; g += 7) {
      while (g - *cons >= RING) __builtin_amdgcn_s_sleep(4);
      unsigned long long v[8];
#pragma unroll
      for (int k = 0; k < 8; k++)
        v[k] = MK[(size_t)g * 512 + k * 64 + lane];
      int slot = g % RING;
#pragma unroll
      for (int k = 0; k < 8; k++)
        ring[slot * 512 + k * 64 + lane] = v[k];
      __threadfence_block();  // data visible before publish
      if (lane == 0) rdy[g] = 1;
    }
  } else {
    // ---------------- consumer wave ----------------
    unsigned long long supp = 0ull, keep = 0ull;
    for (int g = 0; g < 125; g++) {
      while (rdy[g] == 0) { }  // busy-poll: no sleep quantization
      __threadfence_block();
      int slot = g % RING;
      int c = g >> 2;  // owner chunk (16 rows/group, 4 groups/chunk)
      unsigned long long rv[16];
#pragma unroll
      for (int r = 0; r < 16; r++)
        rv[r] = ring[slot * 512 + r * 32 + (lane & 31)];
      unsigned int kg = 0;
      if (lane == c) {
        unsigned long long s = supp;
        int base = (g & 3) * 16;
#pragma unroll
        for (int r = 0; r < 16; r++) {
          int b = base + r;
          if (!((s >> b) & 1ull)) {
            kg |= 1u << r;
            s |= rv[r];
          }
        }
        supp = s;
        keep |= (unsigned long long)kg << base;
      }
      kg = (unsigned int)__shfl((int)kg, c);
      if (lane != c) {
#pragma unroll
        for (int r = 0; r < 16; r++)
          supp |= ((kg >> r) & 1u) ? rv[r] : 0ull;
      }
      __threadfence_block();  // rv reads retired before freeing slot
      if (lane == 63) *cons = g + 1;
    }
    if (lane < 32) kw[lane] = keep;
  }
  __syncthreads();

  // ---------------- fused re-rank (all 8 waves) ----------------
  for (int ch = wave; ch < 32; ch += 8) {
    int i = ch * 64 + lane;
    bool inr = i < NPRE;
    bool kb = inr && ((kw[ch] >> lane) & 1ull);
    bool A = kb && (inr ? (p.selScores[(size_t)t * NPRE + i] > -0.5) : false);
    bool B = inr && !A;
    unsigned long long wa = __ballot(A);
    unsigned long long wb = __ballot(B);
    if (lane == 0) { aw[ch] = wa; bw[ch] = wb; }
  }
  __syncthreads();
  if (tid == 0) {
    unsigned int ca = 0, cb = 0;
    for (int w = 0; w < 32; w++) {
      prefA[w] = ca; ca += __popcll(aw[w]);
      prefB[w] = cb; cb += __popcll(bw[w]);
    }
    prefA[32] = ca; prefB[32] = cb;
  }
  __syncthreads();
  unsigned int KA = prefA[32];
  for (int i = tid; i < NPRE; i += 512) {
    int w = i >> 6, bpos = i & 63;
    unsigned long long below = (bpos == 0) ? 0ull : (~0ull >> (64 - bpos));
    bool kb = (kw[w] >> bpos) & 1ull;
    double s = p.selScores[(size_t)t * NPRE + i];
    bool A = kb && (s > -0.5);
    unsigned int slot;
    double outs;
    if (A) {
      slot = prefA[w] + (unsigned int)__popcll(aw[w] & below);
      outs = s;
    } else {
      slot = KA + prefB[w] + (unsigned int)__popcll(bw[w] & below);
      outs = -1.0;
    }
    if (slot < NPOST) {
      p.postScores[(size_t)t * NPOST + slot] = outs;
      const double* SB = p.selBoxes + ((size_t)t * NPRE + i) * 4;
      float* PB = p.postBoxes + ((size_t)t * NPOST + slot) * 4;
      PB[0] = (float)SB[0]; PB[1] = (float)SB[1];
      PB[2] = (float)SB[2]; PB[3] = (float)SB[3];
    }
  }
}

// --- 8a. final cross-level top-1000: sliced counting-rank (j-outer) ---------
__global__ void k_finalA(RPNParams p) {
  int bx = blockIdx.x;
  int b = bx >> 5;        // image 0..1
  int s = (bx >> 2) & 7;  // j-slice 0..7
  int ec = bx & 3;        // e-chunk 0..3
  int j0 = s * 625;
  __shared__ unsigned long long kj[625];
  int tid = threadIdx.x;  // 256
  for (int j = tid; j < 625; j += 256) {
    int e = j0 + j;
    int l = e / 1000, slot = e - l * 1000;
    int t = l * 2 + b;
    kj[j] = flip64_dev(p.postScores[(size_t)t * NPOST + slot]);
  }
  __syncthreads();
  int eidx[5];
  unsigned long long ke[5];
  unsigned int r[5];
#pragma unroll
  for (int k = 0; k < 5; k++) {
    int e = ec * 1280 + k * 256 + tid;
    eidx[k] = (e < 5000) ? e : -1;
    if (eidx[k] >= 0) {
      int l = e / 1000, slot = e - l * 1000;
      int t = l * 2 + b;
      ke[k] = flip64_dev(p.postScores[(size_t)t * NPOST + slot]);
    } else {
      ke[k] = 0ull;
    }
    r[k] = 0;
  }
  for (int j = 0; j < 625; j++) {
    unsigned long long vj = kj[j];
    int jg = j0 + j;
#pragma unroll
    for (int k = 0; k < 5; k++)
      r[k] += (vj > ke[k] || (vj == ke[k] && jg < eidx[k])) ? 1u : 0u;
  }
#pragma unroll
  for (int k = 0; k < 5; k++)
    if (eidx[k] >= 0)
      p.partial[((size_t)b * 8 + s) * 5000 + eidx[k]] = r[k];
}

// --- 8b. reduce ranks, gather output boxes ----------------------------------
__global__ void k_finalB(RPNParams p) {
  int b = blockIdx.x / 5;
  int ch = blockIdx.x % 5;
  int tid = threadIdx.x;  // 1024
  if (tid < 1000) {
    int e = ch * 1000 + tid;
    unsigned int r = 0;
#pragma unroll
    for (int s = 0; s < 8; s++) r += p.partial[((size_t)b * 8 + s) * 5000 + e];
    if (r < NPOST) {
      int l = e / 1000, slot = e - l * 1000;
      int t = l * 2 + b;
      const float* PB = p.postBoxes + ((size_t)t * NPOST + slot) * 4;
      float* O = p.out + ((size_t)b * NPOST + r) * 4;
      O[0] = PB[0]; O[1] = PB[1]; O[2] = PB[2]; O[3] = PB[3];
    }
  }
}

extern "C" void kernel_launch(void* const* d_in, const int* in_sizes, int n_in,
                              void* d_out, int out_size, void* d_ws,
                              size_t ws_size, hipStream_t stream) {
  RPNParams p;
  bool interleaved = (n_in >= 2) && (in_sizes[1] == 4 * in_sizes[0]);
  for (int l = 0; l < 5; l++) {
    if (interleaved) {
      p.cls[l]  = (const float*)d_in[3 * l + 0];
      p.bbox[l] = (const float*)d_in[3 * l + 1];
      p.anc[l]  = (const float*)d_in[3 * l + 2];
    } else {
      p.cls[l]  = (const float*)d_in[l];
      p.bbox[l] = (const float*)d_in[5 + l];
      p.anc[l]  = (const float*)d_in[10 + l];
    }
  }
  char* w = (char*)d_ws;
  size_t off = 0;
  auto alloc = [&](size_t bytes) {
    off = (off + 255) & ~(size_t)255;
    void* r = w + off;
    off += bytes;
    return r;
  };
  p.hist      = (unsigned int*)alloc((size_t)10 * 65536 * 4);
  p.mainCount = (unsigned int*)alloc(10 * 4);
  p.candCount = (unsigned int*)alloc(10 * 4);
  size_t zbytes = off;  // zeroed region: hist + atomic counters
  p.Bstar      = (unsigned int*)alloc(10 * 4);
  p.mainEK     = (unsigned long long*)alloc((size_t)10 * 2048 * 8);
  p.candEK     = (unsigned long long*)alloc((size_t)10 * 8192 * 8);
  p.ekG        = (unsigned long long*)alloc((size_t)10 * 2048 * 8);
  p.partialR   = (unsigned int*)alloc((size_t)10 * 8 * 2048 * 4);
  p.selBoxes   = (double*)alloc((size_t)10 * NPRE * 4 * 8);
  p.selScores  = (double*)alloc((size_t)10 * NPRE * 8);
  p.mask       = (unsigned long long*)alloc((size_t)10 * NPRE * 32 * 8);
  p.keeps      = (unsigned long long*)alloc((size_t)10 * 32 * 8);
  p.postScores = (double*)alloc((size_t)10 * NPOST * 8);
  p.postBoxes  = (float*)alloc((size_t)10 * NPOST * 4 * 4);
  p.partial    = (unsigned int*)alloc((size_t)16 * 5000 * 4);
  p.out = (float*)d_out;
  (void)ws_size; (void)out_size;

  hipMemsetAsync(d_ws, 0, zbytes, stream);
  k_hist<<<dim3(266), dim3(1024), 0, stream>>>(p);
  k_find<<<dim3(8), dim3(1024), 0, stream>>>(p);
  k_compact<<<dim3(266), dim3(1024), 0, stream>>>(p);
  k_fill<<<dim3(10), dim3(256), 0, stream>>>(p);
  k_rank<<<dim3(80), dim3(256), 0, stream>>>(p);
  k_scatter<<<dim3(10), dim3(1024), 0, stream>>>(p);
  k_iou<<<dim3(100), dim3(1024), 0, stream>>>(p);
  k_greedy<<<dim3(10), dim3(512), 0, stream>>>(p);
  k_finalA<<<dim3(64), dim3(256), 0, stream>>>(p);
  k_finalB<<<dim3(10), dim3(1024), 0, stream>>>(p);
}